// Round 6
// baseline (1839.675 us; speedup 1.0000x reference)
//
#include <hip/hip_runtime.h>
#include <hip/hip_bf16.h>
#include <math.h>

typedef __hip_bfloat16 bf16;

// ---- problem constants ----
// B=128, NC=64, T=1000, SPATIAL_MERGE=32, FILTERS={41,51,61}, NF=192
// FEATURE_DIM = {(3,4),(4,8),(4,16),(7,32),(240,64)}, SUM_SP=1078
// FC_IN = 18528, N_CLASS=4
// Reference input/output dtype: float32 (r6: output switched bf16 -> fp32).

// workspace layout (float offsets)
#define A_OFF    0         // 32*64
#define BETA_OFF 2048      // 32
#define TBE_OFF  2080      // 192
#define TWE_OFF  2304      // exact-size taps: fi offsets {0,2624,5888}, total 9792
#define FLAG_OFF 12288     // 1 float: 1.0 => inputs fp32, 0.0 => bf16
#define XS_OFF   14592     // 128*32*1000 = 4,096,000
#define XBP_OFF  4110592   // 128 * 6 tiles * 64*64 packed  (end 7,256,320 floats)

#define SBN 0.9999950000374997f   // 1/sqrt(1+1e-5)

__device__ __forceinline__ float b2f(bf16 v) { return __bfloat162float(v); }

// dtype-agnostic input load: f!=0 -> fp32, else bf16
__device__ __forceinline__ float ldf(const void* p, int i, int f) {
    return f ? ((const float*)p)[i] : __bfloat162float(((const bf16*)p)[i]);
}

// ---------------------------------------------------------------------------
// K0: input dtype detect (bf16 N(0,1) never has exponent >= 0x9A; fp32 low
// half-words hit it ~40%). Behaviorally confirmed flag=1 (fp32).
// ---------------------------------------------------------------------------
__global__ __launch_bounds__(256) void detect_kernel(const void* __restrict__ x,
                                                     float* __restrict__ ws)
{
    __shared__ int cnt;
    if (threadIdx.x == 0) cnt = 0;
    __syncthreads();
    const unsigned short* u = (const unsigned short*)x;
    int bad = 0;
    for (int i = threadIdx.x; i < 16384; i += 256) {
        int e = (u[i] >> 7) & 0xFF;
        if (e >= 0x9A) ++bad;
    }
    atomicAdd(&cnt, bad);
    __syncthreads();
    if (threadIdx.x == 0) ws[FLAG_OFF] = (cnt > 0) ? 1.0f : 0.0f;
}

// ---------------------------------------------------------------------------
// K1: fold spatial+merge+BN -> A_eff/beta; fold temporal BN -> twe/tbe.
// Reference-faithful iteration: feat index j = joff + f*nc1 + h, tap k = c-h.
// ---------------------------------------------------------------------------
__global__ __launch_bounds__(256) void prep_kernel(
    const void* __restrict__ sw0, const void* __restrict__ sw1,
    const void* __restrict__ sw2, const void* __restrict__ sw3,
    const void* __restrict__ sw4,
    const void* __restrict__ sb0, const void* __restrict__ sb1,
    const void* __restrict__ sb2, const void* __restrict__ sb3,
    const void* __restrict__ sb4,
    const void* __restrict__ mw, const void* __restrict__ mb,
    const void* __restrict__ mg, const void* __restrict__ mbt,
    const void* __restrict__ tw0, const void* __restrict__ tw1,
    const void* __restrict__ tw2,
    const void* __restrict__ tb0, const void* __restrict__ tb1,
    const void* __restrict__ tb2,
    const void* __restrict__ tg0, const void* __restrict__ tg1,
    const void* __restrict__ tg2,
    const void* __restrict__ tbt0, const void* __restrict__ tbt1,
    const void* __restrict__ tbt2,
    float* __restrict__ ws)
{
    const int f = (ws[FLAG_OFF] != 0.0f);
    const void* sws[5]  = {sw0, sw1, sw2, sw3, sw4};
    const void* sbs[5]  = {sb0, sb1, sb2, sb3, sb4};
    const void* tws[3]  = {tw0, tw1, tw2};
    const void* tbs[3]  = {tb0, tb1, tb2};
    const void* tgs[3]  = {tg0, tg1, tg2};
    const void* tbts[3] = {tbt0, tbt1, tbt2};
    const int d0s[5]  = {3, 4, 4, 7, 240};
    const int d1s[5]  = {4, 8, 16, 32, 64};
    const int nc1s[5] = {61, 57, 49, 33, 1};
    const int joffs[5]= {0, 183, 411, 607, 838};

    int id = blockIdx.x * 256 + threadIdx.x;

    if (id < 2048) {
        int m = id >> 6, c = id & 63;
        float acc = 0.f;
        for (int i = 0; i < 5; ++i) {
            int d0 = d0s[i], d1 = d1s[i], nc1 = nc1s[i], joff = joffs[i];
            for (int fq = 0; fq < d0; ++fq) {
                for (int h = 0; h < nc1; ++h) {
                    int k = c - h;
                    if (k >= 0 && k < d1) {
                        int j = joff + fq * nc1 + h;
                        acc += ldf(mw, m * 1078 + j, f) * ldf(sws[i], fq * d1 + k, f);
                    }
                }
            }
        }
        ws[A_OFF + id] = ldf(mg, m, f) * SBN * acc;
    } else if (id < 2080) {
        int m = id - 2048;
        float acc = ldf(mb, m, f);
        for (int i = 0; i < 5; ++i) {
            int d0 = d0s[i], nc1 = nc1s[i], joff = joffs[i];
            for (int fq = 0; fq < d0; ++fq) {
                float sbv = ldf(sbs[i], fq, f);
                for (int h = 0; h < nc1; ++h)
                    acc += ldf(mw, m * 1078 + joff + fq * nc1 + h, f) * sbv;
            }
        }
        ws[BETA_OFF + m] = ldf(mg, m, f) * SBN * acc + ldf(mbt, m, f);
    } else if (id < 2272) {
        int idx = id - 2080;
        int fi = idx >> 6, o = idx & 63;
        ws[TBE_OFF + idx] = ldf(tgs[fi], o, f) * SBN * ldf(tbs[fi], o, f)
                          + ldf(tbts[fi], o, f);
    } else if (id < 12064) {
        int idx = id - 2272;
        int fi, sz, base;
        if (idx < 2624)      { fi = 0; sz = 41; base = 0; }
        else if (idx < 5888) { fi = 1; sz = 51; base = 2624; }
        else                 { fi = 2; sz = 61; base = 5888; }
        int r = idx - base;
        int o = r / sz, k = r - o * sz;
        ws[TWE_OFF + idx] = ldf(tgs[fi], o, f) * SBN * ldf(tws[fi], o * sz + k, f);
    }
}

// ---------------------------------------------------------------------------
// K2: Xs[b][m][t] = A_eff[m,:] . x[b,:,t] + beta[m]
// ---------------------------------------------------------------------------
__global__ __launch_bounds__(256) void xs_kernel(const void* __restrict__ x,
                                                 float* __restrict__ ws)
{
    __shared__ float Ash[2048];
    __shared__ float Bsh[32];
    int tid = threadIdx.x;
    const int f = (ws[FLAG_OFF] != 0.0f);
    for (int i = tid; i < 2048; i += 256) Ash[i] = ws[A_OFF + i];
    if (tid < 32) Bsh[tid] = ws[BETA_OFF + tid];
    __syncthreads();

    int gid = blockIdx.x * 256 + tid;       // 0..127999 (500 blocks)
    int b = gid / 1000, t = gid - b * 1000;
    int xbase = b * 64000 + t;

    float acc[32];
#pragma unroll
    for (int m = 0; m < 32; ++m) acc[m] = Bsh[m];
#pragma unroll 4
    for (int c = 0; c < 64; ++c) {
        float xv = ldf(x, xbase + c * 1000, f);
#pragma unroll
        for (int m = 0; m < 32; ++m) acc[m] += Ash[m * 64 + c] * xv;
    }
    float* op = ws + XS_OFF + b * 32000 + t;
#pragma unroll
    for (int m = 0; m < 32; ++m) op[m * 1000] = acc[m];
}

// ---------------------------------------------------------------------------
// K3: temporal conv (naive per-tap) + covariance.
// grid = 128 batches * 6 lower-triangle 64x64 tiles.
// ---------------------------------------------------------------------------
__global__ __launch_bounds__(256) void cov_kernel(float* __restrict__ ws)
{
    __shared__ float xs_sh[32 * 129];   // Xs chunk, 30-halo each side
    __shared__ float xt_sh[2 * 4224];   // 64t x 64o, stride 66
    __shared__ float tw_sh[7168];       // I bank then J bank, [k][o] layout
    __shared__ float tb_sh[128];

    int tid = threadIdx.x;
    int wg = blockIdx.x;
    int b = wg / 6, tile = wg - b * 6;
    const int TIa[6] = {0, 1, 1, 2, 2, 2};
    const int TJa[6] = {0, 0, 1, 0, 1, 2};
    int I = TIa[tile], J = TJa[tile];
    const int fsz[3]   = {41, 51, 61};
    const int fpad[3]  = {20, 25, 30};
    const int twoff[3] = {0, 2624, 5888};
    int szI = fsz[I], padI = fpad[I];
    int szJ = fsz[J], padJ = fpad[J];
    bool diag = (I == J);

    int nI = szI * 64;
    for (int idx = tid; idx < nI; idx += 256) {
        int kt = idx >> 6, o = idx & 63;
        tw_sh[idx] = ws[TWE_OFF + twoff[I] + o * szI + kt];
    }
    if (!diag) {
        int nJ = szJ * 64;
        for (int idx = tid; idx < nJ; idx += 256) {
            int kt = idx >> 6, o = idx & 63;
            tw_sh[nI + idx] = ws[TWE_OFF + twoff[J] + o * szJ + kt];
        }
    }
    if (tid < 64)        tb_sh[tid] = ws[TBE_OFF + I * 64 + tid];
    else if (tid < 128)  tb_sh[tid] = ws[TBE_OFF + J * 64 + (tid - 64)];

    float acc[4][4];
#pragma unroll
    for (int i = 0; i < 4; ++i)
#pragma unroll
        for (int j = 0; j < 4; ++j) acc[i][j] = 0.f;

    int tx = tid & 15, ty = tid >> 4;
    const float* xsrow = ws + XS_OFF + b * 32000;
    float* xtI = xt_sh;
    float* xtJ = diag ? xt_sh : (xt_sh + 4224);
    const int o  = tid & 63;
    const int wv = tid >> 6;
    const int m  = o >> 1;

    for (int t0 = 0; t0 < 1000; t0 += 64) {
        __syncthreads();
        for (int idx = tid; idx < 4096; idx += 256) {
            int mm = idx >> 7, q = idx & 127;
            int gt = t0 - 30 + q;
            xs_sh[mm * 129 + q] = (gt >= 0 && gt < 1000) ? xsrow[mm * 1000 + gt] : 0.f;
        }
        __syncthreads();
        for (int u = 0; u < 16; ++u) {
            int tl = wv * 16 + u;
            int gt = t0 + tl;
            {
                float a = tb_sh[o];
                const float* xr = &xs_sh[m * 129 + tl + 30 - padI];
                for (int k = 0; k < szI; ++k) a += tw_sh[k * 64 + o] * xr[k];
                xtI[tl * 66 + o] = (gt < 1000) ? a : 0.f;
            }
            if (!diag) {
                float a = tb_sh[64 + o];
                const float* xr = &xs_sh[m * 129 + tl + 30 - padJ];
                for (int k = 0; k < szJ; ++k) a += tw_sh[nI + k * 64 + o] * xr[k];
                xtJ[tl * 66 + o] = (gt < 1000) ? a : 0.f;
            }
        }
        __syncthreads();
#pragma unroll 2
        for (int k = 0; k < 64; ++k) {
            const float* ar = &xtI[k * 66 + 4 * ty];
            const float* br = &xtJ[k * 66 + 4 * tx];
            float av[4] = {ar[0], ar[1], ar[2], ar[3]};
            float bv[4] = {br[0], br[1], br[2], br[3]};
#pragma unroll
            for (int i = 0; i < 4; ++i)
#pragma unroll
                for (int j = 0; j < 4; ++j) acc[i][j] += av[i] * bv[j];
        }
    }

    float* xbp = ws + XBP_OFF + b * 24576 + tile * 4096;
    const float sc = 1.0f / 999.0f;
#pragma unroll
    for (int i = 0; i < 4; ++i)
#pragma unroll
        for (int j = 0; j < 4; ++j)
            xbp[(4 * ty + i) * 64 + (4 * tx + j)] = acc[i][j] * sc;
}

// ---------------------------------------------------------------------------
// K4: per-batch Cholesky (packed triangle, 75KB LDS) + fused tangent/FC.
// r6: OUTPUT IS FLOAT32 (reference output dtype), not bf16.
// ---------------------------------------------------------------------------
__global__ __launch_bounds__(256) void chol_kernel(const float* __restrict__ ws,
                                                   const void* __restrict__ fcw,
                                                   const void* __restrict__ fcb,
                                                   float* __restrict__ out)
{
    __shared__ float Lp[18528];
    __shared__ float col[192];
    __shared__ float red[4][4];

    int b = blockIdx.x, tid = threadIdx.x;
    const int f = (ws[FLAG_OFF] != 0.0f);
    const float* Xb = ws + XBP_OFF + b * 24576;

    for (int p = tid; p < 18528; p += 256) {
        float fp = (float)p;
        int r = (int)((sqrtf(8.0f * fp + 1.0f) - 1.0f) * 0.5f);
        if (r < 0) r = 0;
        while (r * (r + 1) / 2 > p) --r;
        while ((r + 1) * (r + 2) / 2 <= p) ++r;
        int c = p - r * (r + 1) / 2;
        int bi = r >> 6, bj = c >> 6;
        int tile = bi * (bi + 1) / 2 + bj;
        float g = Xb[tile * 4096 + (r & 63) * 64 + (c & 63)];
        Lp[p] = isfinite(g) ? g : 0.f;
    }
    __syncthreads();

    for (int j = 0; j < 192; ++j) {
        int dj = j * (j + 1) / 2;
        float d = Lp[dj + j];
        d = fmaxf(d, 1e-20f);
        float inv = 1.0f / sqrtf(d);
        int i = j + 1 + tid;
        if (i < 192) {
            float v = Lp[i * (i + 1) / 2 + j] * inv;
            v = fminf(fmaxf(v, -1e6f), 1e6f);
            col[i] = v;
            Lp[i * (i + 1) / 2 + j] = v;
        }
        __syncthreads();
        if (tid == 0) Lp[dj + j] = d * inv;
        int R = 191 - j;
        int half = (R + 1) >> 1;
        if (tid < half) {
            int i1 = j + 1 + tid;
            int i2 = 191 - tid;
            {
                float c1 = col[i1];
                float* row1 = &Lp[i1 * (i1 + 1) / 2];
                for (int k = j + 1; k <= i1; ++k) row1[k] -= c1 * col[k];
            }
            if (i2 > i1) {
                float c2 = col[i2];
                float* row2 = &Lp[i2 * (i2 + 1) / 2];
                for (int k = j + 1; k <= i2; ++k) row2[k] -= c2 * col[k];
            }
        }
        __syncthreads();
    }

    float a0 = 0.f, a1 = 0.f, a2 = 0.f, a3 = 0.f;
    for (int d = tid; d < 192; d += 256) {
        float v = logf(fmaxf(Lp[d * (d + 1) / 2 + d], 1e-30f));
        a0 += v * ldf(fcw, d, f);
        a1 += v * ldf(fcw, 18528 + d, f);
        a2 += v * ldf(fcw, 2 * 18528 + d, f);
        a3 += v * ldf(fcw, 3 * 18528 + d, f);
    }
    for (int e = tid; e < 18336; e += 256) {
        float fe = (float)e;
        int r = (int)((1.0f + sqrtf(1.0f + 8.0f * fe)) * 0.5f);
        if (r < 1) r = 1;
        while (r * (r - 1) / 2 > e) --r;
        while ((r + 1) * r / 2 <= e) ++r;
        int c = e - r * (r - 1) / 2;
        float v = Lp[r * (r + 1) / 2 + c];
        int dd = 192 + e;
        a0 += v * ldf(fcw, dd, f);
        a1 += v * ldf(fcw, 18528 + dd, f);
        a2 += v * ldf(fcw, 2 * 18528 + dd, f);
        a3 += v * ldf(fcw, 3 * 18528 + dd, f);
    }
    for (int off = 32; off > 0; off >>= 1) {
        a0 += __shfl_down(a0, off);
        a1 += __shfl_down(a1, off);
        a2 += __shfl_down(a2, off);
        a3 += __shfl_down(a3, off);
    }
    int wv = tid >> 6, ln = tid & 63;
    if (ln == 0) { red[wv][0] = a0; red[wv][1] = a1; red[wv][2] = a2; red[wv][3] = a3; }
    __syncthreads();
    if (tid < 4) {
        float s = red[0][tid] + red[1][tid] + red[2][tid] + red[3][tid] + ldf(fcb, tid, f);
        out[b * 4 + tid] = s;   // fp32 output per reference dtype
    }
}

// ---------------------------------------------------------------------------
extern "C" void kernel_launch(void* const* d_in, const int* in_sizes, int n_in,
                              void* d_out, int out_size, void* d_ws, size_t ws_size,
                              hipStream_t stream)
{
    float* ws = (float*)d_ws;

    detect_kernel<<<1, 256, 0, stream>>>(d_in[0], ws);
    prep_kernel<<<48, 256, 0, stream>>>(d_in[1], d_in[3], d_in[5], d_in[7], d_in[9],
                                        d_in[2], d_in[4], d_in[6], d_in[8], d_in[10],
                                        d_in[11], d_in[12], d_in[13], d_in[14],
                                        d_in[15], d_in[19], d_in[23],
                                        d_in[16], d_in[20], d_in[24],
                                        d_in[17], d_in[21], d_in[25],
                                        d_in[18], d_in[22], d_in[26], ws);
    xs_kernel<<<500, 256, 0, stream>>>(d_in[0], ws);
    cov_kernel<<<768, 256, 0, stream>>>(ws);
    chol_kernel<<<128, 256, 0, stream>>>(ws, d_in[27], d_in[28], (float*)d_out);
}

// Round 7
// 935.069 us; speedup vs baseline: 1.9674x; 1.9674x over previous
//
#include <hip/hip_runtime.h>
#include <hip/hip_bf16.h>
#include <math.h>

// ---- problem constants ----
// B=128, NC=64, T=1000, SPATIAL_MERGE=32, FILTERS={41,51,61}, NF=192
// FEATURE_DIM = {(3,4),(4,8),(4,16),(7,32),(240,64)}, SUM_SP=1078
// FC_IN = 18528, N_CLASS=4
// Input/output dtype: float32 (behaviorally confirmed r1-r6).

// workspace layout (float offsets) — 29 MB envelope (proven addressable)
#define A_OFF    0         // 32*64
#define BETA_OFF 2048      // 32
#define TBE_OFF  2080      // 192
#define TWE_OFF  2304      // 3*4096, taps zero-padded to 64
#define XS_OFF   14592     // 128*32*1000 = 4,096,000
#define XBP_OFF  4110592   // 128 * 6 tiles * 64*64 packed (end 7,256,320 floats)

#define SBN 0.9999950000374997f   // 1/sqrt(1+1e-5)

// ---------------------------------------------------------------------------
// K1: fold spatial+merge+BN -> A_eff/beta; fold temporal BN -> twe (padded to
// 64 taps for the rolling-window conv) / tbe. Reference-faithful iteration.
// ---------------------------------------------------------------------------
__global__ __launch_bounds__(256) void prep_kernel(
    const float* __restrict__ sw0, const float* __restrict__ sw1,
    const float* __restrict__ sw2, const float* __restrict__ sw3,
    const float* __restrict__ sw4,
    const float* __restrict__ sb0, const float* __restrict__ sb1,
    const float* __restrict__ sb2, const float* __restrict__ sb3,
    const float* __restrict__ sb4,
    const float* __restrict__ mw, const float* __restrict__ mb,
    const float* __restrict__ mg, const float* __restrict__ mbt,
    const float* __restrict__ tw0, const float* __restrict__ tw1,
    const float* __restrict__ tw2,
    const float* __restrict__ tb0, const float* __restrict__ tb1,
    const float* __restrict__ tb2,
    const float* __restrict__ tg0, const float* __restrict__ tg1,
    const float* __restrict__ tg2,
    const float* __restrict__ tbt0, const float* __restrict__ tbt1,
    const float* __restrict__ tbt2,
    float* __restrict__ ws)
{
    const float* sws[5]  = {sw0, sw1, sw2, sw3, sw4};
    const float* sbs[5]  = {sb0, sb1, sb2, sb3, sb4};
    const float* tws[3]  = {tw0, tw1, tw2};
    const float* tbs[3]  = {tb0, tb1, tb2};
    const float* tgs[3]  = {tg0, tg1, tg2};
    const float* tbts[3] = {tbt0, tbt1, tbt2};
    const int d0s[5]  = {3, 4, 4, 7, 240};
    const int d1s[5]  = {4, 8, 16, 32, 64};
    const int nc1s[5] = {61, 57, 49, 33, 1};
    const int joffs[5]= {0, 183, 411, 607, 838};
    const int fsz[3]  = {41, 51, 61};

    int id = blockIdx.x * 256 + threadIdx.x;

    if (id < 2048) {
        // A_eff[m][c] = mg*SBN * sum_j mw[m,j] * sw_i[f, c-h]  (j=joff+f*nc1+h)
        int m = id >> 6, c = id & 63;
        float acc = 0.f;
        for (int i = 0; i < 5; ++i) {
            int d0 = d0s[i], d1 = d1s[i], nc1 = nc1s[i], joff = joffs[i];
            for (int fq = 0; fq < d0; ++fq) {
                for (int h = 0; h < nc1; ++h) {
                    int k = c - h;
                    if (k >= 0 && k < d1)
                        acc += mw[m * 1078 + joff + fq * nc1 + h] * sws[i][fq * d1 + k];
                }
            }
        }
        ws[A_OFF + id] = mg[m] * SBN * acc;
    } else if (id < 2080) {
        int m = id - 2048;
        float acc = mb[m];
        for (int i = 0; i < 5; ++i) {
            int d0 = d0s[i], nc1 = nc1s[i], joff = joffs[i];
            for (int fq = 0; fq < d0; ++fq) {
                float sbv = sbs[i][fq];
                for (int h = 0; h < nc1; ++h)
                    acc += mw[m * 1078 + joff + fq * nc1 + h] * sbv;
            }
        }
        ws[BETA_OFF + m] = mg[m] * SBN * acc + mbt[m];
    } else if (id < 2272) {
        int idx = id - 2080;
        int fi = idx >> 6, o = idx & 63;
        ws[TBE_OFF + idx] = tgs[fi][o] * SBN * tbs[fi][o] + tbts[fi][o];
    } else if (id < 14560) {
        // twe[fi][o][k], taps zero-padded to 64 (rolling-window conv wants pad)
        int idx = id - 2272;
        int fi = idx >> 12, r = idx & 4095, o = r >> 6, k = r & 63;
        int sz = fsz[fi];
        float v = 0.f;
        if (k < sz) v = tgs[fi][o] * SBN * tws[fi][o * sz + k];
        ws[TWE_OFF + idx] = v;
    }
}

// ---------------------------------------------------------------------------
// K2: Xs[b][m][t] = A_eff[m,:] . x[b,:,t] + beta[m]
// ---------------------------------------------------------------------------
__global__ __launch_bounds__(256) void xs_kernel(const float* __restrict__ x,
                                                 float* __restrict__ ws)
{
    __shared__ float Ash[2048];
    __shared__ float Bsh[32];
    int tid = threadIdx.x;
    for (int i = tid; i < 2048; i += 256) Ash[i] = ws[A_OFF + i];
    if (tid < 32) Bsh[tid] = ws[BETA_OFF + tid];
    __syncthreads();

    int gid = blockIdx.x * 256 + tid;       // 0..127999 (500 blocks)
    int b = gid / 1000, t = gid - b * 1000;
    const float* xp = x + b * 64000 + t;

    float acc[32];
#pragma unroll
    for (int m = 0; m < 32; ++m) acc[m] = Bsh[m];
#pragma unroll 4
    for (int c = 0; c < 64; ++c) {
        float xv = xp[c * 1000];
#pragma unroll
        for (int m = 0; m < 32; ++m) acc[m] += Ash[m * 64 + c] * xv;
    }
    float* op = ws + XS_OFF + b * 32000 + t;
#pragma unroll
    for (int m = 0; m < 32; ++m) op[m * 1000] = acc[m];
}

// ---------------------------------------------------------------------------
// K3: temporal conv (rolling 8-output register window, 1 LDS read / 8 FMA —
// numerically identical to naive per-tap, verified r4==r5) + covariance.
// grid = 128 batches * 6 lower-triangle 64x64 tiles.
// ---------------------------------------------------------------------------
__device__ __forceinline__ void conv8_store(float* __restrict__ xt,
                                            const float* __restrict__ xp,
                                            const float* __restrict__ wp,
                                            int szp, float bias,
                                            int tlb, int o, int t0)
{
    float a[8], xw[8];
#pragma unroll
    for (int i = 0; i < 8; ++i) { a[i] = bias; xw[i] = xp[i]; }
    for (int k = 0; k < szp; k += 8) {
#pragma unroll
        for (int p = 0; p < 8; ++p) {
            float w = wp[(k + p) * 64];
#pragma unroll
            for (int i = 0; i < 8; ++i) a[i] += w * xw[(p + i) & 7];
            xw[p] = xp[k + p + 8];
        }
    }
#pragma unroll
    for (int i = 0; i < 8; ++i) {
        int gt = t0 + tlb + i;
        xt[(tlb + i) * 66 + o] = (gt < 1000) ? a[i] : 0.f;
    }
}

__global__ __launch_bounds__(256) void cov_kernel(float* __restrict__ ws)
{
    __shared__ float xs_sh[32 * 129];   // 16,512 B
    __shared__ float xt_sh[2 * 4224];   // 33,792 B
    __shared__ float tw_sh[7680];       // 30,720 B  [k][o] transposed, padded
    __shared__ float tb_sh[128];
    // ~81.5 KB -> 2 WG/CU

    int tid = threadIdx.x;
    int wg = blockIdx.x;
    int b = wg / 6, tile = wg - b * 6;
    const int TIa[6] = {0, 1, 1, 2, 2, 2};
    const int TJa[6] = {0, 0, 1, 0, 1, 2};
    int I = TIa[tile], J = TJa[tile];
    const int fpad[3] = {20, 25, 30};
    const int fszp[3] = {48, 56, 64};   // taps padded to multiple of 8
    int padI = fpad[I], szpI = fszp[I];
    int padJ = fpad[J], szpJ = fszp[J];
    bool diag = (I == J);

    int nI = szpI * 64;
    for (int idx = tid; idx < nI; idx += 256) {
        int kt = idx >> 6, o = idx & 63;
        tw_sh[idx] = ws[TWE_OFF + I * 4096 + o * 64 + kt];
    }
    if (!diag) {
        int nJ = szpJ * 64;
        for (int idx = tid; idx < nJ; idx += 256) {
            int kt = idx >> 6, o = idx & 63;
            tw_sh[nI + idx] = ws[TWE_OFF + J * 4096 + o * 64 + kt];
        }
    }
    if (tid < 64)        tb_sh[tid] = ws[TBE_OFF + I * 64 + tid];
    else if (tid < 128)  tb_sh[tid] = ws[TBE_OFF + J * 64 + (tid - 64)];

    float acc[4][4];
#pragma unroll
    for (int i = 0; i < 4; ++i)
#pragma unroll
        for (int j = 0; j < 4; ++j) acc[i][j] = 0.f;

    int tx = tid & 15, ty = tid >> 4;
    const float* xsrow = ws + XS_OFF + b * 32000;
    float* xtI = xt_sh;
    float* xtJ = diag ? xt_sh : (xt_sh + 4224);

    for (int t0 = 0; t0 < 1000; t0 += 64) {
        __syncthreads();
        // stage Xs chunk with 30-halo, zero-padded
        for (int idx = tid; idx < 4096; idx += 256) {
            int m = idx >> 7, q = idx & 127;
            int gt = t0 - 30 + q;
            xs_sh[m * 129 + q] = (gt >= 0 && gt < 1000) ? xsrow[m * 1000 + gt] : 0.f;
        }
        __syncthreads();
        // rolling-window temporal conv
        for (int it = 0; it < 2; ++it) {
            int o   = tid & 63;
            int grp = (tid >> 6) + it * 4;   // 0..7
            int tlb = grp * 8;
            int m   = o >> 1;
            conv8_store(xtI, &xs_sh[m * 129 + tlb + (30 - padI)], &tw_sh[o],
                        szpI, tb_sh[o], tlb, o, t0);
            if (!diag)
                conv8_store(xtJ, &xs_sh[m * 129 + tlb + (30 - padJ)], &tw_sh[nI + o],
                            szpJ, tb_sh[64 + o], tlb, o, t0);
        }
        __syncthreads();
        // covariance accumulate, 4x4 microtile
#pragma unroll 2
        for (int k = 0; k < 64; ++k) {
            const float* ar = &xtI[k * 66 + 4 * ty];
            const float* br = &xtJ[k * 66 + 4 * tx];
            float av[4] = {ar[0], ar[1], ar[2], ar[3]};
            float bv[4] = {br[0], br[1], br[2], br[3]};
#pragma unroll
            for (int i = 0; i < 4; ++i)
#pragma unroll
                for (int j = 0; j < 4; ++j) acc[i][j] += av[i] * bv[j];
        }
    }

    float* xbp = ws + XBP_OFF + b * 24576 + tile * 4096;
    const float sc = 1.0f / 999.0f;
#pragma unroll
    for (int i = 0; i < 4; ++i)
#pragma unroll
        for (int j = 0; j < 4; ++j)
            xbp[(4 * ty + i) * 64 + (4 * tx + j)] = acc[i][j] * sc;
}

// ---------------------------------------------------------------------------
// K4: per-batch BLOCKED Cholesky (NB=16), square LDS layout stride 193 (odd:
// conflict-free), trailing rank-16 update with 4x4 register tiles. Fused
// log-diag / tril-flatten / FC epilogue. fp32 out.
// ---------------------------------------------------------------------------
__global__ __launch_bounds__(256) void chol_kernel(const float* __restrict__ ws,
                                                   const float* __restrict__ fcw,
                                                   const float* __restrict__ fcb,
                                                   float* __restrict__ out)
{
    __shared__ float L[192 * 193];   // 148,224 B -> 1 WG/CU (128 WGs on 256 CUs)
    __shared__ float red[4][4];

    int b = blockIdx.x, tid = threadIdx.x;
    const float* Xb = ws + XBP_OFF + b * 24576;
    const int TIa[6] = {0, 1, 1, 2, 2, 2};
    const int TJa[6] = {0, 0, 1, 0, 1, 2};

    // load packed tiles into lower-triangle region of square layout
    for (int idx = tid; idx < 24576; idx += 256) {
        int t = idx >> 12, r = (idx >> 6) & 63, c = idx & 63;
        L[(TIa[t] * 64 + r) * 193 + TJa[t] * 64 + c] = Xb[idx];
    }
    __syncthreads();

    for (int p = 0; p < 12; ++p) {
        int j0 = p * 16, j1 = j0 + 16;
        // --- panel factorization (cols j0..j1-1, all rows) ---
        for (int jj = 0; jj < 16; ++jj) {
            int j = j0 + jj;
            float d = fmaxf(L[j * 193 + j], 1e-20f);   // broadcast read
            float inv = 1.0f / sqrtf(d);
            for (int i = j + 1 + tid; i < 192; i += 256) L[i * 193 + j] *= inv;
            __syncthreads();
            if (tid == 0) L[j * 193 + j] = d * inv;    // = sqrt(d)
            // rank-1 update confined to remaining panel columns
            for (int j2 = j + 1; j2 < j1; ++j2) {
                float lj2 = L[j2 * 193 + j];
                for (int i = j2 + tid; i < 192; i += 256)
                    L[i * 193 + j2] -= L[i * 193 + j] * lj2;
            }
            __syncthreads();
        }
        // --- trailing rank-16 update: A[j1:,j1:] -= P P^T, 4x4 reg tiles ---
        if (j1 < 192) {
            int RT = (192 - j1) >> 2;
            int ntiles = RT * (RT + 1) / 2;
            for (int t = tid; t < ntiles; t += 256) {
                int ti = (int)((sqrtf(8.0f * (float)t + 1.0f) - 1.0f) * 0.5f);
                while (ti * (ti + 1) / 2 > t) --ti;
                while ((ti + 1) * (ti + 2) / 2 <= t) ++ti;
                int tj = t - ti * (ti + 1) / 2;
                int i0 = j1 + 4 * ti, c0 = j1 + 4 * tj;
                float a[4][4];
#pragma unroll
                for (int r = 0; r < 4; ++r)
#pragma unroll
                    for (int c = 0; c < 4; ++c)
                        a[r][c] = L[(i0 + r) * 193 + c0 + c];
#pragma unroll
                for (int k = 0; k < 16; ++k) {
                    float ar[4], bc[4];
#pragma unroll
                    for (int r = 0; r < 4; ++r) ar[r] = L[(i0 + r) * 193 + j0 + k];
#pragma unroll
                    for (int c = 0; c < 4; ++c) bc[c] = L[(c0 + c) * 193 + j0 + k];
#pragma unroll
                    for (int r = 0; r < 4; ++r)
#pragma unroll
                        for (int c = 0; c < 4; ++c)
                            a[r][c] -= ar[r] * bc[c];
                }
#pragma unroll
                for (int r = 0; r < 4; ++r)
#pragma unroll
                    for (int c = 0; c < 4; ++c)
                        L[(i0 + r) * 193 + c0 + c] = a[r][c];
            }
        }
        __syncthreads();
    }

    // fused tangent + FC:  out[b,k] = fcb[k] + sum_d tangent[d]*fcw[k][d]
    float a0 = 0.f, a1 = 0.f, a2 = 0.f, a3 = 0.f;
    for (int d = tid; d < 192; d += 256) {
        float v = logf(fmaxf(L[d * 193 + d], 1e-30f));
        a0 += v * fcw[d];
        a1 += v * fcw[18528 + d];
        a2 += v * fcw[2 * 18528 + d];
        a3 += v * fcw[3 * 18528 + d];
    }
    for (int e = tid; e < 18336; e += 256) {
        float fe = (float)e;
        int r = (int)((1.0f + sqrtf(1.0f + 8.0f * fe)) * 0.5f);
        if (r < 1) r = 1;
        while (r * (r - 1) / 2 > e) --r;
        while ((r + 1) * r / 2 <= e) ++r;
        int c = e - r * (r - 1) / 2;
        float v = L[r * 193 + c];
        int dd = 192 + e;
        a0 += v * fcw[dd];
        a1 += v * fcw[18528 + dd];
        a2 += v * fcw[2 * 18528 + dd];
        a3 += v * fcw[3 * 18528 + dd];
    }
    for (int off = 32; off > 0; off >>= 1) {
        a0 += __shfl_down(a0, off);
        a1 += __shfl_down(a1, off);
        a2 += __shfl_down(a2, off);
        a3 += __shfl_down(a3, off);
    }
    int wv = tid >> 6, ln = tid & 63;
    if (ln == 0) { red[wv][0] = a0; red[wv][1] = a1; red[wv][2] = a2; red[wv][3] = a3; }
    __syncthreads();
    if (tid < 4) {
        float s = red[0][tid] + red[1][tid] + red[2][tid] + red[3][tid] + fcb[tid];
        out[b * 4 + tid] = s;
    }
}

// ---------------------------------------------------------------------------
extern "C" void kernel_launch(void* const* d_in, const int* in_sizes, int n_in,
                              void* d_out, int out_size, void* d_ws, size_t ws_size,
                              hipStream_t stream)
{
    float* ws = (float*)d_ws;

    prep_kernel<<<57, 256, 0, stream>>>(
        (const float*)d_in[1], (const float*)d_in[3], (const float*)d_in[5],
        (const float*)d_in[7], (const float*)d_in[9],
        (const float*)d_in[2], (const float*)d_in[4], (const float*)d_in[6],
        (const float*)d_in[8], (const float*)d_in[10],
        (const float*)d_in[11], (const float*)d_in[12], (const float*)d_in[13],
        (const float*)d_in[14],
        (const float*)d_in[15], (const float*)d_in[19], (const float*)d_in[23],
        (const float*)d_in[16], (const float*)d_in[20], (const float*)d_in[24],
        (const float*)d_in[17], (const float*)d_in[21], (const float*)d_in[25],
        (const float*)d_in[18], (const float*)d_in[22], (const float*)d_in[26], ws);
    xs_kernel<<<500, 256, 0, stream>>>((const float*)d_in[0], ws);
    cov_kernel<<<768, 256, 0, stream>>>(ws);
    chol_kernel<<<128, 256, 0, stream>>>(ws, (const float*)d_in[27],
                                         (const float*)d_in[28], (float*)d_out);
}

// Round 8
// 705.280 us; speedup vs baseline: 2.6084x; 1.3258x over previous
//
#include <hip/hip_runtime.h>
#include <hip/hip_bf16.h>
#include <math.h>

// ---- problem constants ----
// B=128, NC=64, T=1000, SPATIAL_MERGE=32, FILTERS={41,51,61}, NF=192
// FEATURE_DIM = {(3,4),(4,8),(4,16),(7,32),(240,64)}, SUM_SP=1078
// FC_IN = 18528, N_CLASS=4.  Input/output dtype: float32 (confirmed r6/r7).

// workspace layout (float offsets) — 29 MB envelope (proven addressable)
#define A_OFF    0         // 32*64
#define BETA_OFF 2048      // 32
#define TBE_OFF  2080      // 192
#define TWE_OFF  2304      // 3*4096, taps zero-padded to 64
#define XS_OFF   14592     // 128*32*1000 = 4,096,000
#define XBP_OFF  4110592   // 128 * 6 tiles * 64*64 packed (end 7,256,320 floats)

#define SBN 0.9999950000374997f   // 1/sqrt(1+1e-5)

typedef short short8 __attribute__((ext_vector_type(8)));    // 8 bf16 bits (4 VGPRs)
typedef float floatx4 __attribute__((ext_vector_type(4)));   // MFMA accumulator

__device__ __forceinline__ unsigned short f2bf(float f) {    // fp32 -> bf16 (RNE)
    unsigned u = __float_as_uint(f);
    u += 0x7FFFu + ((u >> 16) & 1u);
    return (unsigned short)(u >> 16);
}
__device__ __forceinline__ float bf2f(unsigned short h) {
    return __uint_as_float(((unsigned)h) << 16);
}

#define WAVE_SYNC() asm volatile("s_waitcnt lgkmcnt(0)" ::: "memory")

// ---------------------------------------------------------------------------
// K1: fold spatial+merge+BN -> A_eff/beta; fold temporal BN -> twe/tbe.
// (unchanged from r7 — verified)
// ---------------------------------------------------------------------------
__global__ __launch_bounds__(256) void prep_kernel(
    const float* __restrict__ sw0, const float* __restrict__ sw1,
    const float* __restrict__ sw2, const float* __restrict__ sw3,
    const float* __restrict__ sw4,
    const float* __restrict__ sb0, const float* __restrict__ sb1,
    const float* __restrict__ sb2, const float* __restrict__ sb3,
    const float* __restrict__ sb4,
    const float* __restrict__ mw, const float* __restrict__ mb,
    const float* __restrict__ mg, const float* __restrict__ mbt,
    const float* __restrict__ tw0, const float* __restrict__ tw1,
    const float* __restrict__ tw2,
    const float* __restrict__ tb0, const float* __restrict__ tb1,
    const float* __restrict__ tb2,
    const float* __restrict__ tg0, const float* __restrict__ tg1,
    const float* __restrict__ tg2,
    const float* __restrict__ tbt0, const float* __restrict__ tbt1,
    const float* __restrict__ tbt2,
    float* __restrict__ ws)
{
    const float* sws[5]  = {sw0, sw1, sw2, sw3, sw4};
    const float* sbs[5]  = {sb0, sb1, sb2, sb3, sb4};
    const float* tws[3]  = {tw0, tw1, tw2};
    const float* tbs[3]  = {tb0, tb1, tb2};
    const float* tgs[3]  = {tg0, tg1, tg2};
    const float* tbts[3] = {tbt0, tbt1, tbt2};
    const int d0s[5]  = {3, 4, 4, 7, 240};
    const int d1s[5]  = {4, 8, 16, 32, 64};
    const int nc1s[5] = {61, 57, 49, 33, 1};
    const int joffs[5]= {0, 183, 411, 607, 838};
    const int fsz[3]  = {41, 51, 61};

    int id = blockIdx.x * 256 + threadIdx.x;

    if (id < 2048) {
        int m = id >> 6, c = id & 63;
        float acc = 0.f;
        for (int i = 0; i < 5; ++i) {
            int d0 = d0s[i], d1 = d1s[i], nc1 = nc1s[i], joff = joffs[i];
            for (int fq = 0; fq < d0; ++fq) {
                for (int h = 0; h < nc1; ++h) {
                    int k = c - h;
                    if (k >= 0 && k < d1)
                        acc += mw[m * 1078 + joff + fq * nc1 + h] * sws[i][fq * d1 + k];
                }
            }
        }
        ws[A_OFF + id] = mg[m] * SBN * acc;
    } else if (id < 2080) {
        int m = id - 2048;
        float acc = mb[m];
        for (int i = 0; i < 5; ++i) {
            int d0 = d0s[i], nc1 = nc1s[i], joff = joffs[i];
            for (int fq = 0; fq < d0; ++fq) {
                float sbv = sbs[i][fq];
                for (int h = 0; h < nc1; ++h)
                    acc += mw[m * 1078 + joff + fq * nc1 + h] * sbv;
            }
        }
        ws[BETA_OFF + m] = mg[m] * SBN * acc + mbt[m];
    } else if (id < 2272) {
        int idx = id - 2080;
        int fi = idx >> 6, o = idx & 63;
        ws[TBE_OFF + idx] = tgs[fi][o] * SBN * tbs[fi][o] + tbts[fi][o];
    } else if (id < 14560) {
        int idx = id - 2272;
        int fi = idx >> 12, r = idx & 4095, o = r >> 6, k = r & 63;
        int sz = fsz[fi];
        float v = 0.f;
        if (k < sz) v = tgs[fi][o] * SBN * tws[fi][o * sz + k];
        ws[TWE_OFF + idx] = v;
    }
}

// ---------------------------------------------------------------------------
// K2: Xs[b][m][t] = A_eff[m,:] . x[b,:,t] + beta[m]  (unchanged — verified)
// ---------------------------------------------------------------------------
__global__ __launch_bounds__(256) void xs_kernel(const float* __restrict__ x,
                                                 float* __restrict__ ws)
{
    __shared__ float Ash[2048];
    __shared__ float Bsh[32];
    int tid = threadIdx.x;
    for (int i = tid; i < 2048; i += 256) Ash[i] = ws[A_OFF + i];
    if (tid < 32) Bsh[tid] = ws[BETA_OFF + tid];
    __syncthreads();

    int gid = blockIdx.x * 256 + tid;       // 0..127999 (500 blocks)
    int b = gid / 1000, t = gid - b * 1000;
    const float* xp = x + b * 64000 + t;

    float acc[32];
#pragma unroll
    for (int m = 0; m < 32; ++m) acc[m] = Bsh[m];
#pragma unroll 4
    for (int c = 0; c < 64; ++c) {
        float xv = xp[c * 1000];
#pragma unroll
        for (int m = 0; m < 32; ++m) acc[m] += Ash[m * 64 + c] * xv;
    }
    float* op = ws + XS_OFF + b * 32000 + t;
#pragma unroll
    for (int m = 0; m < 32; ++m) op[m * 1000] = acc[m];
}

// ---------------------------------------------------------------------------
// K3: temporal conv (rolling 8-out window, bf16 weights from LDS) + MFMA Gram.
// xt stored bf16 [o][t] stride 72 (16B-aligned rows, 2-way-free banks).
// Gram tile 64x64 via mfma_f32_16x16x32_bf16, gemm-bt fragment pattern
// (A row-frags from XtI, B row-frags from XtJ; C/D col=lane&15,row=quad*4+reg).
// LDS 50.8 KB -> 3 blocks/CU; grid 768 = 256 CU x 3 exactly (no tail).
// ---------------------------------------------------------------------------
__device__ __forceinline__ void conv8_bf(unsigned short* __restrict__ xt,
                                         const float* __restrict__ xp,
                                         const unsigned short* __restrict__ wp,
                                         int szp, float bias,
                                         int tlb, int o, int t0)
{
    float a[8], xw[8];
#pragma unroll
    for (int i = 0; i < 8; ++i) { a[i] = bias; xw[i] = xp[i]; }
    for (int k = 0; k < szp; k += 8) {
#pragma unroll
        for (int p = 0; p < 8; ++p) {
            float w = bf2f(wp[(k + p) * 64]);
#pragma unroll
            for (int i = 0; i < 8; ++i) a[i] += w * xw[(p + i) & 7];
            xw[p] = xp[k + p + 8];
        }
    }
    short8 hv;
#pragma unroll
    for (int i = 0; i < 8; ++i) {
        int gt = t0 + tlb + i;
        float v = (gt < 1000) ? a[i] : 0.f;
        hv[i] = (short)f2bf(v);
    }
    *(short8*)&xt[o * 72 + tlb] = hv;   // 16B-aligned (144*o + 2*tlb, tlb%8==0)
}

__global__ __launch_bounds__(256, 3) void cov_kernel(float* __restrict__ ws)
{
    __shared__ float xs_sh[32 * 129];                         // 16,512 B
    __shared__ __align__(16) unsigned short xt_sh[2 * 64 * 72]; // 18,432 B
    __shared__ unsigned short tw_sh[120 * 64];                // 15,360 B (bf16)
    __shared__ float tb_sh[128];                              //     512 B
    // total 50,816 B -> 3 blocks/CU

    int tid = threadIdx.x;
    int wg = blockIdx.x;
    int b = wg / 6, tile = wg - b * 6;
    const int TIa[6] = {0, 1, 1, 2, 2, 2};
    const int TJa[6] = {0, 0, 1, 0, 1, 2};
    int I = TIa[tile], J = TJa[tile];
    const int fpad[3] = {20, 25, 30};
    const int fszp[3] = {48, 56, 64};   // taps padded to multiple of 8
    int padI = fpad[I], szpI = fszp[I];
    int padJ = fpad[J], szpJ = fszp[J];
    bool diag = (I == J);

    int nI = szpI * 64;
    for (int idx = tid; idx < nI; idx += 256) {
        int kt = idx >> 6, o = idx & 63;
        tw_sh[idx] = f2bf(ws[TWE_OFF + I * 4096 + o * 64 + kt]);
    }
    if (!diag) {
        int nJ = szpJ * 64;
        for (int idx = tid; idx < nJ; idx += 256) {
            int kt = idx >> 6, o = idx & 63;
            tw_sh[nI + idx] = f2bf(ws[TWE_OFF + J * 4096 + o * 64 + kt]);
        }
    }
    if (tid < 64)        tb_sh[tid] = ws[TBE_OFF + I * 64 + tid];
    else if (tid < 128)  tb_sh[tid] = ws[TBE_OFF + J * 64 + (tid - 64)];

    floatx4 acc[4];
#pragma unroll
    for (int sj = 0; sj < 4; ++sj) acc[sj] = (floatx4){0.f, 0.f, 0.f, 0.f};

    const float* xsrow = ws + XS_OFF + b * 32000;
    unsigned short* xtI = xt_sh;
    unsigned short* xtJ = diag ? xt_sh : (xt_sh + 64 * 72);

    const int lane = tid & 63;
    const int wv   = tid >> 6;
    const int m15  = lane & 15;
    const int quad = lane >> 4;

    for (int t0 = 0; t0 < 1000; t0 += 64) {
        // stage Xs chunk with 30-halo (writes xs only; safe vs in-flight MFMA)
        for (int idx = tid; idx < 4096; idx += 256) {
            int m = idx >> 7, q = idx & 127;
            int gt = t0 - 30 + q;
            xs_sh[m * 129 + q] = (gt >= 0 && gt < 1000) ? xsrow[m * 1000 + gt] : 0.f;
        }
        __syncthreads();   // xs ready; all prior MFMA done -> xt free
        // rolling-window conv -> bf16 xt
        for (int it = 0; it < 2; ++it) {
            int o   = lane;
            int grp = wv + it * 4;     // 0..7
            int tlb = grp * 8;
            int m   = o >> 1;
            conv8_bf(xtI, &xs_sh[m * 129 + tlb + (30 - padI)], &tw_sh[o],
                     szpI, tb_sh[o], tlb, o, t0);
            if (!diag)
                conv8_bf(xtJ, &xs_sh[m * 129 + tlb + (30 - padJ)], &tw_sh[nI + o],
                         szpJ, tb_sh[64 + o], tlb, o, t0);
        }
        __syncthreads();   // xt ready; xs free for next chunk's staging
        // MFMA Gram accumulate: wave wv owns row-strip si=wv, all 4 sj subtiles
        const unsigned short* ap = &xtI[(wv * 16 + m15) * 72 + quad * 8];
#pragma unroll
        for (int k0 = 0; k0 < 64; k0 += 32) {
            short8 af = *(const short8*)(ap + k0);
#pragma unroll
            for (int sj = 0; sj < 4; ++sj) {
                short8 bf = *(const short8*)&xtJ[(sj * 16 + m15) * 72 + quad * 8 + k0];
                acc[sj] = __builtin_amdgcn_mfma_f32_16x16x32_bf16(af, bf, acc[sj],
                                                                  0, 0, 0);
            }
        }
    }

    float* xbp = ws + XBP_OFF + b * 24576 + tile * 4096;
    const float sc = 1.0f / 999.0f;
#pragma unroll
    for (int sj = 0; sj < 4; ++sj)
#pragma unroll
        for (int r = 0; r < 4; ++r) {
            int i = wv * 16 + quad * 4 + r;     // C/D: row = quad*4 + reg
            int j = sj * 16 + m15;              //      col = lane & 15
            xbp[i * 64 + j] = acc[sj][r] * sc;
        }
}

// ---------------------------------------------------------------------------
// K4: per-batch blocked Cholesky (NB=16): wave0 lockstep diag-block factor
// (no block barriers), parallel-row TRSM (no inner barriers), rank-16
// trailing update with 4x4 reg tiles (r7-verified). ~3 barriers/panel.
// Fused log-diag / tril-flatten / FC epilogue. fp32 out.
// ---------------------------------------------------------------------------
__global__ __launch_bounds__(256) void chol_kernel(const float* __restrict__ ws,
                                                   const float* __restrict__ fcw,
                                                   const float* __restrict__ fcb,
                                                   float* __restrict__ out)
{
    __shared__ float L[192 * 193];   // 148,224 B -> 1 block/CU
    __shared__ float red[4][4];

    int b = blockIdx.x, tid = threadIdx.x;
    const float* Xb = ws + XBP_OFF + b * 24576;
    const int TIa[6] = {0, 1, 1, 2, 2, 2};
    const int TJa[6] = {0, 0, 1, 0, 1, 2};

    for (int idx = tid; idx < 24576; idx += 256) {
        int t = idx >> 12, r = (idx >> 6) & 63, c = idx & 63;
        L[(TIa[t] * 64 + r) * 193 + TJa[t] * 64 + c] = Xb[idx];
    }
    __syncthreads();

    for (int p = 0; p < 12; ++p) {
        int j0 = p * 16, j1 = j0 + 16;
        // --- A: 16x16 diag block Cholesky, wave 0 only (lockstep, no barriers)
        if (tid < 64) {
            for (int jj = 0; jj < 16; ++jj) {
                int j = j0 + jj;
                float d = fmaxf(L[j * 193 + j], 1e-20f);
                float s = sqrtf(d);
                float inv = 1.0f / s;
                if (tid == jj) L[j * 193 + j] = s;
                if (tid > jj && tid < 16) L[(j0 + tid) * 193 + j] *= inv;
                WAVE_SYNC();
                if (tid > jj && tid < 16) {
                    float vi = L[(j0 + tid) * 193 + j];
                    for (int c = jj + 1; c <= tid; ++c)
                        L[(j0 + tid) * 193 + j0 + c] -= vi * L[(j0 + c) * 193 + j];
                }
                WAVE_SYNC();
            }
        }
        __syncthreads();
        if (j1 < 192) {
            // --- B: TRSM, one row per thread, serial-k in registers
            int i = j1 + tid;
            if (i < 192) {
                float v[16];
                float* row = &L[i * 193 + j0];
#pragma unroll
                for (int k = 0; k < 16; ++k) v[k] = row[k];
#pragma unroll
                for (int k = 0; k < 16; ++k) {
                    float vk = v[k];
#pragma unroll
                    for (int p2 = 0; p2 < k; ++p2)
                        vk -= v[p2] * L[(j0 + k) * 193 + j0 + p2];
                    v[k] = vk / L[(j0 + k) * 193 + j0 + k];
                }
#pragma unroll
                for (int k = 0; k < 16; ++k) row[k] = v[k];
            }
            __syncthreads();
            // --- C: trailing rank-16 update, 4x4 reg tiles (r7-verified)
            int RT = (192 - j1) >> 2;
            int ntiles = RT * (RT + 1) / 2;
            for (int t = tid; t < ntiles; t += 256) {
                int ti = (int)((sqrtf(8.0f * (float)t + 1.0f) - 1.0f) * 0.5f);
                while (ti * (ti + 1) / 2 > t) --ti;
                while ((ti + 1) * (ti + 2) / 2 <= t) ++ti;
                int tj = t - ti * (ti + 1) / 2;
                int i0 = j1 + 4 * ti, c0 = j1 + 4 * tj;
                float a[4][4];
#pragma unroll
                for (int r = 0; r < 4; ++r)
#pragma unroll
                    for (int c = 0; c < 4; ++c)
                        a[r][c] = L[(i0 + r) * 193 + c0 + c];
#pragma unroll
                for (int k = 0; k < 16; ++k) {
                    float ar[4], bc[4];
#pragma unroll
                    for (int r = 0; r < 4; ++r) ar[r] = L[(i0 + r) * 193 + j0 + k];
#pragma unroll
                    for (int c = 0; c < 4; ++c) bc[c] = L[(c0 + c) * 193 + j0 + k];
#pragma unroll
                    for (int r = 0; r < 4; ++r)
#pragma unroll
                        for (int c = 0; c < 4; ++c)
                            a[r][c] -= ar[r] * bc[c];
                }
#pragma unroll
                for (int r = 0; r < 4; ++r)
#pragma unroll
                    for (int c = 0; c < 4; ++c)
                        L[(i0 + r) * 193 + c0 + c] = a[r][c];
            }
        }
        __syncthreads();
    }

    // fused tangent + FC:  out[b,k] = fcb[k] + sum_d tangent[d]*fcw[k][d]
    float a0 = 0.f, a1 = 0.f, a2 = 0.f, a3 = 0.f;
    for (int d = tid; d < 192; d += 256) {
        float v = logf(fmaxf(L[d * 193 + d], 1e-30f));
        a0 += v * fcw[d];
        a1 += v * fcw[18528 + d];
        a2 += v * fcw[2 * 18528 + d];
        a3 += v * fcw[3 * 18528 + d];
    }
    for (int e = tid; e < 18336; e += 256) {
        float fe = (float)e;
        int r = (int)((1.0f + sqrtf(1.0f + 8.0f * fe)) * 0.5f);
        if (r < 1) r = 1;
        while (r * (r - 1) / 2 > e) --r;
        while ((r + 1) * r / 2 <= e) ++r;
        int c = e - r * (r - 1) / 2;
        float v = L[r * 193 + c];
        int dd = 192 + e;
        a0 += v * fcw[dd];
        a1 += v * fcw[18528 + dd];
        a2 += v * fcw[2 * 18528 + dd];
        a3 += v * fcw[3 * 18528 + dd];
    }
    for (int off = 32; off > 0; off >>= 1) {
        a0 += __shfl_down(a0, off);
        a1 += __shfl_down(a1, off);
        a2 += __shfl_down(a2, off);
        a3 += __shfl_down(a3, off);
    }
    int wv = tid >> 6, ln = tid & 63;
    if (ln == 0) { red[wv][0] = a0; red[wv][1] = a1; red[wv][2] = a2; red[wv][3] = a3; }
    __syncthreads();
    if (tid < 4) {
        float s = red[0][tid] + red[1][tid] + red[2][tid] + red[3][tid] + fcb[tid];
        out[b * 4 + tid] = s;
    }
}

// ---------------------------------------------------------------------------
extern "C" void kernel_launch(void* const* d_in, const int* in_sizes, int n_in,
                              void* d_out, int out_size, void* d_ws, size_t ws_size,
                              hipStream_t stream)
{
    float* ws = (float*)d_ws;

    prep_kernel<<<57, 256, 0, stream>>>(
        (const float*)d_in[1], (const float*)d_in[3], (const float*)d_in[5],
        (const float*)d_in[7], (const float*)d_in[9],
        (const float*)d_in[2], (const float*)d_in[4], (const float*)d_in[6],
        (const float*)d_in[8], (const float*)d_in[10],
        (const float*)d_in[11], (const float*)d_in[12], (const float*)d_in[13],
        (const float*)d_in[14],
        (const float*)d_in[15], (const float*)d_in[19], (const float*)d_in[23],
        (const float*)d_in[16], (const float*)d_in[20], (const float*)d_in[24],
        (const float*)d_in[17], (const float*)d_in[21], (const float*)d_in[25],
        (const float*)d_in[18], (const float*)d_in[22], (const float*)d_in[26], ws);
    xs_kernel<<<500, 256, 0, stream>>>((const float*)d_in[0], ws);
    cov_kernel<<<768, 256, 0, stream>>>(ws);
    chol_kernel<<<128, 256, 0, stream>>>(ws, (const float*)d_in[27],
                                         (const float*)d_in[28], (float*)d_out);
}

// Round 9
// 507.891 us; speedup vs baseline: 3.6222x; 1.3886x over previous
//
#include <hip/hip_runtime.h>
#include <hip/hip_bf16.h>
#include <math.h>

// ---- problem constants ----
// B=128, NC=64, T=1000, SPATIAL_MERGE=32, FILTERS={41,51,61}, NF=192
// FEATURE_DIM = {(3,4),(4,8),(4,16),(7,32),(240,64)}, SUM_SP=1078
// FC_IN = 18528, N_CLASS=4.  Input/output dtype: float32 (confirmed r6/r7).

// workspace layout (float offsets)
#define A_OFF    0         // 32*64
#define BETA_OFF 2048      // 32
#define TBE_OFF  2080      // 192
#define TWE_OFF  2304      // 3*4096, taps zero-padded to 64
#define XS_OFF   14592     // 128*32*1000 = 4,096,000
#define XBP_OFF  4110592   // 128 * 6 tiles * 64*64 packed (end 7,256,320 floats)
#define XT_OFF   7256320   // bf16 Xt [b][192][1024] = 12,582,912 floats worth
#define WS_NEED  ((size_t)19839232 * 4)   // 79.4 MB -> split path; else fused

#define SBN 0.9999950000374997f   // 1/sqrt(1+1e-5)

typedef short short8 __attribute__((ext_vector_type(8)));    // 8 bf16 (4 VGPRs)
typedef float floatx4 __attribute__((ext_vector_type(4)));   // MFMA accumulator

__device__ __forceinline__ unsigned short f2bf(float f) {    // fp32 -> bf16 (RNE)
    unsigned u = __float_as_uint(f);
    u += 0x7FFFu + ((u >> 16) & 1u);
    return (unsigned short)(u >> 16);
}
__device__ __forceinline__ float bf2f(unsigned short h) {
    return __uint_as_float(((unsigned)h) << 16);
}

// ---------------------------------------------------------------------------
// K1: fold spatial+merge+BN -> A_eff/beta; fold temporal BN -> twe/tbe.
// (verified r6-r8)
// ---------------------------------------------------------------------------
__global__ __launch_bounds__(256) void prep_kernel(
    const float* __restrict__ sw0, const float* __restrict__ sw1,
    const float* __restrict__ sw2, const float* __restrict__ sw3,
    const float* __restrict__ sw4,
    const float* __restrict__ sb0, const float* __restrict__ sb1,
    const float* __restrict__ sb2, const float* __restrict__ sb3,
    const float* __restrict__ sb4,
    const float* __restrict__ mw, const float* __restrict__ mb,
    const float* __restrict__ mg, const float* __restrict__ mbt,
    const float* __restrict__ tw0, const float* __restrict__ tw1,
    const float* __restrict__ tw2,
    const float* __restrict__ tb0, const float* __restrict__ tb1,
    const float* __restrict__ tb2,
    const float* __restrict__ tg0, const float* __restrict__ tg1,
    const float* __restrict__ tg2,
    const float* __restrict__ tbt0, const float* __restrict__ tbt1,
    const float* __restrict__ tbt2,
    float* __restrict__ ws)
{
    const float* sws[5]  = {sw0, sw1, sw2, sw3, sw4};
    const float* sbs[5]  = {sb0, sb1, sb2, sb3, sb4};
    const float* tws[3]  = {tw0, tw1, tw2};
    const float* tbs[3]  = {tb0, tb1, tb2};
    const float* tgs[3]  = {tg0, tg1, tg2};
    const float* tbts[3] = {tbt0, tbt1, tbt2};
    const int d0s[5]  = {3, 4, 4, 7, 240};
    const int d1s[5]  = {4, 8, 16, 32, 64};
    const int nc1s[5] = {61, 57, 49, 33, 1};
    const int joffs[5]= {0, 183, 411, 607, 838};
    const int fsz[3]  = {41, 51, 61};

    int id = blockIdx.x * 256 + threadIdx.x;

    if (id < 2048) {
        int m = id >> 6, c = id & 63;
        float acc = 0.f;
        for (int i = 0; i < 5; ++i) {
            int d0 = d0s[i], d1 = d1s[i], nc1 = nc1s[i], joff = joffs[i];
            for (int fq = 0; fq < d0; ++fq) {
                for (int h = 0; h < nc1; ++h) {
                    int k = c - h;
                    if (k >= 0 && k < d1)
                        acc += mw[m * 1078 + joff + fq * nc1 + h] * sws[i][fq * d1 + k];
                }
            }
        }
        ws[A_OFF + id] = mg[m] * SBN * acc;
    } else if (id < 2080) {
        int m = id - 2048;
        float acc = mb[m];
        for (int i = 0; i < 5; ++i) {
            int d0 = d0s[i], nc1 = nc1s[i], joff = joffs[i];
            for (int fq = 0; fq < d0; ++fq) {
                float sbv = sbs[i][fq];
                for (int h = 0; h < nc1; ++h)
                    acc += mw[m * 1078 + joff + fq * nc1 + h] * sbv;
            }
        }
        ws[BETA_OFF + m] = mg[m] * SBN * acc + mbt[m];
    } else if (id < 2272) {
        int idx = id - 2080;
        int fi = idx >> 6, o = idx & 63;
        ws[TBE_OFF + idx] = tgs[fi][o] * SBN * tbs[fi][o] + tbts[fi][o];
    } else if (id < 14560) {
        int idx = id - 2272;
        int fi = idx >> 12, r = idx & 4095, o = r >> 6, k = r & 63;
        int sz = fsz[fi];
        float v = 0.f;
        if (k < sz) v = tgs[fi][o] * SBN * tws[fi][o * sz + k];
        ws[TWE_OFF + idx] = v;
    }
}

// ---------------------------------------------------------------------------
// K2: Xs[b][m][t] = A_eff[m,:] . x[b,:,t] + beta[m]  (verified)
// ---------------------------------------------------------------------------
__global__ __launch_bounds__(256) void xs_kernel(const float* __restrict__ x,
                                                 float* __restrict__ ws)
{
    __shared__ float Ash[2048];
    __shared__ float Bsh[32];
    int tid = threadIdx.x;
    for (int i = tid; i < 2048; i += 256) Ash[i] = ws[A_OFF + i];
    if (tid < 32) Bsh[tid] = ws[BETA_OFF + tid];
    __syncthreads();

    int gid = blockIdx.x * 256 + tid;
    int b = gid / 1000, t = gid - b * 1000;
    const float* xp = x + b * 64000 + t;

    float acc[32];
#pragma unroll
    for (int m = 0; m < 32; ++m) acc[m] = Bsh[m];
#pragma unroll 4
    for (int c = 0; c < 64; ++c) {
        float xv = xp[c * 1000];
#pragma unroll
        for (int m = 0; m < 32; ++m) acc[m] += Ash[m * 64 + c] * xv;
    }
    float* op = ws + XS_OFF + b * 32000 + t;
#pragma unroll
    for (int m = 0; m < 32; ++m) op[m * 1000] = acc[m];
}

// ---------------------------------------------------------------------------
// conv8: rolling 8-output register window, bf16 weights (verified r8)
// ---------------------------------------------------------------------------
__device__ __forceinline__ void conv8_vals(float* __restrict__ a,
                                           const float* __restrict__ xp,
                                           const unsigned short* __restrict__ wp,
                                           int szp, float bias)
{
    float xw[8];
#pragma unroll
    for (int i = 0; i < 8; ++i) { a[i] = bias; xw[i] = xp[i]; }
    for (int k = 0; k < szp; k += 8) {
#pragma unroll
        for (int p = 0; p < 8; ++p) {
            float w = bf2f(wp[(k + p) * 64]);
#pragma unroll
            for (int i = 0; i < 8; ++i) a[i] += w * xw[(p + i) & 7];
            xw[p] = xp[k + p + 8];
        }
    }
}

// ---------------------------------------------------------------------------
// K3a (split path): compute Xt bf16 ONCE to global ws[b][192][1024].
// grid = 128 b x 8 t-chunks (TC=128). No redundancy (r8 fused had 3x).
// ---------------------------------------------------------------------------
__global__ __launch_bounds__(256) void xt_kernel(float* __restrict__ ws)
{
    __shared__ float xs_sh[32 * 200];              // 25,600 B, width 200 halo
    __shared__ unsigned short tw_sh[10752];        // 21,504 B (3 banks, [k][o])
    __shared__ float tb_sh[192];
    // ~47.9 KB -> 3 blocks/CU

    int tid = threadIdx.x;
    int wg = blockIdx.x;
    int b = wg >> 3, chunk = wg & 7;
    int t0 = chunk * 128;
    const int fszp[3]  = {48, 56, 64};
    const int fpad[3]  = {20, 25, 30};
    const int twoff[3] = {0, 3072, 6656};          // 48*64, +56*64

    // stage all 3 banks' weights (bf16) + biases
    for (int idx = tid; idx < 10752; idx += 256) {
        int bank, kt, rem;
        if (idx < 3072)      { bank = 0; rem = idx; }
        else if (idx < 6656) { bank = 1; rem = idx - 3072; }
        else                 { bank = 2; rem = idx - 6656; }
        kt = rem >> 6; int o = rem & 63;
        tw_sh[idx] = f2bf(ws[TWE_OFF + bank * 4096 + o * 64 + kt]);
    }
    if (tid < 192) tb_sh[tid] = ws[TBE_OFF + tid];

    // stage Xs chunk with halo
    const float* xsrow = ws + XS_OFF + b * 32000;
    for (int idx = tid; idx < 6400; idx += 256) {
        int m = idx / 200, q = idx - m * 200;
        int gt = t0 - 30 + q;
        xs_sh[m * 200 + q] = (gt >= 0 && gt < 1000) ? xsrow[m * 1000 + gt] : 0.f;
    }
    __syncthreads();

    unsigned short* xtg = (unsigned short*)(ws + XT_OFF);
    // 192 ch x 16 t-groups = 3072 tasks, 12 per thread
    for (int it = 0; it < 12; ++it) {
        int task = it * 256 + tid;
        int ch = task >> 4, tg = task & 15;
        int bank = ch >> 6, o = ch & 63, m = o >> 1;
        int tlb = tg * 8;
        float a[8];
        conv8_vals(a, &xs_sh[m * 200 + tlb + (30 - fpad[bank])],
                   &tw_sh[twoff[bank] + o], fszp[bank], tb_sh[ch]);
        short8 hv;
#pragma unroll
        for (int i = 0; i < 8; ++i) {
            int gt = t0 + tlb + i;
            hv[i] = (short)((gt < 1000) ? f2bf(a[i]) : 0);
        }
        *(short8*)&xtg[(size_t)(b * 192 + ch) * 1024 + t0 + tlb] = hv;
    }
}

// ---------------------------------------------------------------------------
// K3b (split path): Gram via bf16 MFMA, K=1024 (zero-padded tail).
// grid = 128 b x 6 lower-triangle tiles. LDS stride 136 ushort (aligned 16B).
// ---------------------------------------------------------------------------
__global__ __launch_bounds__(256) void gram_kernel(float* __restrict__ ws)
{
    __shared__ __align__(16) unsigned short xa_sh[64 * 136];  // 17,408 B
    __shared__ __align__(16) unsigned short xb_sh[64 * 136];  // 17,408 B

    int tid = threadIdx.x;
    int wg = blockIdx.x;
    int b = wg / 6, tile = wg - b * 6;
    const int TIa[6] = {0, 1, 1, 2, 2, 2};
    const int TJa[6] = {0, 0, 1, 0, 1, 2};
    int I = TIa[tile], J = TJa[tile];
    bool diag = (I == J);

    const unsigned short* xtg = (const unsigned short*)(ws + XT_OFF);
    const unsigned short* gI = xtg + (size_t)(b * 192 + I * 64) * 1024;
    const unsigned short* gJ = xtg + (size_t)(b * 192 + J * 64) * 1024;

    floatx4 acc[4];
#pragma unroll
    for (int sj = 0; sj < 4; ++sj) acc[sj] = (floatx4){0.f, 0.f, 0.f, 0.f};

    const int lane = tid & 63;
    const int wv   = tid >> 6;
    const int m15  = lane & 15;
    const int quad = lane >> 4;
    unsigned short* xbp_sh = diag ? xa_sh : xb_sh;

    for (int t0 = 0; t0 < 1024; t0 += 128) {
        // stage K-chunk: 64 rows x 128 cols per bank
        for (int idx = tid; idx < 1024; idx += 256) {
            int row = idx >> 4, c8 = idx & 15;
            *(short8*)&xa_sh[row * 136 + c8 * 8] =
                *(const short8*)&gI[(size_t)row * 1024 + t0 + c8 * 8];
        }
        if (!diag) {
            for (int idx = tid; idx < 1024; idx += 256) {
                int row = idx >> 4, c8 = idx & 15;
                *(short8*)&xb_sh[row * 136 + c8 * 8] =
                    *(const short8*)&gJ[(size_t)row * 1024 + t0 + c8 * 8];
            }
        }
        __syncthreads();
#pragma unroll
        for (int k0 = 0; k0 < 128; k0 += 32) {
            short8 af = *(const short8*)&xa_sh[(wv * 16 + m15) * 136 + quad * 8 + k0];
#pragma unroll
            for (int sj = 0; sj < 4; ++sj) {
                short8 bf = *(const short8*)&xbp_sh[(sj * 16 + m15) * 136 + quad * 8 + k0];
                acc[sj] = __builtin_amdgcn_mfma_f32_16x16x32_bf16(af, bf, acc[sj],
                                                                  0, 0, 0);
            }
        }
        __syncthreads();
    }

    float* xbp = ws + XBP_OFF + b * 24576 + tile * 4096;
    const float sc = 1.0f / 999.0f;
#pragma unroll
    for (int sj = 0; sj < 4; ++sj)
#pragma unroll
        for (int r = 0; r < 4; ++r) {
            int i = wv * 16 + quad * 4 + r;     // C/D: row = quad*4 + reg
            int j = sj * 16 + m15;              //      col = lane & 15
            xbp[i * 64 + j] = acc[sj][r] * sc;
        }
}

// ---------------------------------------------------------------------------
// K3 (fallback path, ws too small): r8's fused conv+Gram kernel (verified).
// ---------------------------------------------------------------------------
__global__ __launch_bounds__(256, 3) void cov_kernel(float* __restrict__ ws)
{
    __shared__ float xs_sh[32 * 129];
    __shared__ __align__(16) unsigned short xt_sh[2 * 64 * 72];
    __shared__ unsigned short tw_sh[120 * 64];
    __shared__ float tb_sh[128];

    int tid = threadIdx.x;
    int wg = blockIdx.x;
    int b = wg / 6, tile = wg - b * 6;
    const int TIa[6] = {0, 1, 1, 2, 2, 2};
    const int TJa[6] = {0, 0, 1, 0, 1, 2};
    int I = TIa[tile], J = TJa[tile];
    const int fpad[3] = {20, 25, 30};
    const int fszp[3] = {48, 56, 64};
    int padI = fpad[I], szpI = fszp[I];
    int padJ = fpad[J], szpJ = fszp[J];
    bool diag = (I == J);

    int nI = szpI * 64;
    for (int idx = tid; idx < nI; idx += 256) {
        int kt = idx >> 6, o = idx & 63;
        tw_sh[idx] = f2bf(ws[TWE_OFF + I * 4096 + o * 64 + kt]);
    }
    if (!diag) {
        int nJ = szpJ * 64;
        for (int idx = tid; idx < nJ; idx += 256) {
            int kt = idx >> 6, o = idx & 63;
            tw_sh[nI + idx] = f2bf(ws[TWE_OFF + J * 4096 + o * 64 + kt]);
        }
    }
    if (tid < 64)        tb_sh[tid] = ws[TBE_OFF + I * 64 + tid];
    else if (tid < 128)  tb_sh[tid] = ws[TBE_OFF + J * 64 + (tid - 64)];

    floatx4 acc[4];
#pragma unroll
    for (int sj = 0; sj < 4; ++sj) acc[sj] = (floatx4){0.f, 0.f, 0.f, 0.f};

    const float* xsrow = ws + XS_OFF + b * 32000;
    unsigned short* xtI = xt_sh;
    unsigned short* xtJ = diag ? xt_sh : (xt_sh + 64 * 72);

    const int lane = tid & 63;
    const int wv   = tid >> 6;
    const int m15  = lane & 15;
    const int quad = lane >> 4;

    for (int t0 = 0; t0 < 1000; t0 += 64) {
        for (int idx = tid; idx < 4096; idx += 256) {
            int m = idx >> 7, q = idx & 127;
            int gt = t0 - 30 + q;
            xs_sh[m * 129 + q] = (gt >= 0 && gt < 1000) ? xsrow[m * 1000 + gt] : 0.f;
        }
        __syncthreads();
        for (int it = 0; it < 2; ++it) {
            int o   = lane;
            int grp = wv + it * 4;
            int tlb = grp * 8;
            int m   = o >> 1;
            float a[8];
            conv8_vals(a, &xs_sh[m * 129 + tlb + (30 - padI)], &tw_sh[o],
                       szpI, tb_sh[o]);
            short8 hv;
#pragma unroll
            for (int i = 0; i < 8; ++i) {
                int gt = t0 + tlb + i;
                hv[i] = (short)((gt < 1000) ? f2bf(a[i]) : 0);
            }
            *(short8*)&xtI[o * 72 + tlb] = hv;
            if (!diag) {
                conv8_vals(a, &xs_sh[m * 129 + tlb + (30 - padJ)], &tw_sh[nI + o],
                           szpJ, tb_sh[64 + o]);
#pragma unroll
                for (int i = 0; i < 8; ++i) {
                    int gt = t0 + tlb + i;
                    hv[i] = (short)((gt < 1000) ? f2bf(a[i]) : 0);
                }
                *(short8*)&xtJ[o * 72 + tlb] = hv;
            }
        }
        __syncthreads();
        const unsigned short* ap = &xtI[(wv * 16 + m15) * 72 + quad * 8];
#pragma unroll
        for (int k0 = 0; k0 < 64; k0 += 32) {
            short8 af = *(const short8*)(ap + k0);
#pragma unroll
            for (int sj = 0; sj < 4; ++sj) {
                short8 bf = *(const short8*)&xtJ[(sj * 16 + m15) * 72 + quad * 8 + k0];
                acc[sj] = __builtin_amdgcn_mfma_f32_16x16x32_bf16(af, bf, acc[sj],
                                                                  0, 0, 0);
            }
        }
        __syncthreads();
    }

    float* xbp = ws + XBP_OFF + b * 24576 + tile * 4096;
    const float sc = 1.0f / 999.0f;
#pragma unroll
    for (int sj = 0; sj < 4; ++sj)
#pragma unroll
        for (int r = 0; r < 4; ++r) {
            int i = wv * 16 + quad * 4 + r;
            int j = sj * 16 + m15;
            xbp[i * 64 + j] = acc[sj][r] * sc;
        }
}

// ---------------------------------------------------------------------------
// K4: per-batch blocked Cholesky (NB=16). Panel diag block factored entirely
// in registers of lanes 0-15 via __shfl (no LDS latency chain, no syncs);
// TRSM uses precomputed inv-diag (no divides); rank-16 trailing update with
// 4x4 reg tiles (r7/r8-verified). Fused log/tril/FC epilogue. fp32 out.
// ---------------------------------------------------------------------------
__global__ __launch_bounds__(256) void chol_kernel(const float* __restrict__ ws,
                                                   const float* __restrict__ fcw,
                                                   const float* __restrict__ fcb,
                                                   float* __restrict__ out)
{
    __shared__ float L[192 * 193];   // 148,224 B
    __shared__ float invd_sh[16];
    __shared__ float red[4][4];

    int b = blockIdx.x, tid = threadIdx.x;
    const float* Xb = ws + XBP_OFF + b * 24576;
    const int TIa[6] = {0, 1, 1, 2, 2, 2};
    const int TJa[6] = {0, 0, 1, 0, 1, 2};

    for (int idx = tid; idx < 24576; idx += 256) {
        int t = idx >> 12, r = (idx >> 6) & 63, c = idx & 63;
        L[(TIa[t] * 64 + r) * 193 + TJa[t] * 64 + c] = Xb[idx];
    }
    __syncthreads();

    for (int p = 0; p < 12; ++p) {
        int j0 = p * 16, j1 = j0 + 16;
        // --- A: 16x16 diag Cholesky in registers (lanes 0-15, shuffles) ---
        if (tid < 16) {
            int i = tid;
            float r[16];
#pragma unroll
            for (int c = 0; c < 16; ++c) r[c] = L[(j0 + i) * 193 + j0 + c];
#pragma unroll
            for (int jj = 0; jj < 16; ++jj) {
                float d = __shfl(r[jj], jj);
                d = fmaxf(d, 1e-20f);
                float s = sqrtf(d);
                float inv = 1.0f / s;
                if (i == jj) { r[jj] = s; invd_sh[jj] = inv; }
                else if (i > jj) r[jj] *= inv;
#pragma unroll
                for (int cc = jj + 1; cc < 16; ++cc) {
                    float vc = __shfl(r[jj], cc);
                    if (i >= cc) r[cc] -= r[jj] * vc;
                }
            }
#pragma unroll
            for (int c = 0; c < 16; ++c)
                if (c <= i) L[(j0 + i) * 193 + j0 + c] = r[c];
        }
        __syncthreads();
        if (j1 < 192) {
            // --- B: TRSM, one row per thread, inv-diag multiplies ---
            int i = j1 + tid;
            if (i < 192) {
                float v[16];
                float* row = &L[i * 193 + j0];
#pragma unroll
                for (int k = 0; k < 16; ++k) v[k] = row[k];
#pragma unroll
                for (int k = 0; k < 16; ++k) {
                    float vk = v[k];
#pragma unroll
                    for (int p2 = 0; p2 < k; ++p2)
                        vk -= v[p2] * L[(j0 + k) * 193 + j0 + p2];
                    v[k] = vk * invd_sh[k];
                }
#pragma unroll
                for (int k = 0; k < 16; ++k) row[k] = v[k];
            }
            __syncthreads();
            // --- C: trailing rank-16 update, 4x4 reg tiles ---
            int RT = (192 - j1) >> 2;
            int ntiles = RT * (RT + 1) / 2;
            for (int t = tid; t < ntiles; t += 256) {
                int ti = (int)((sqrtf(8.0f * (float)t + 1.0f) - 1.0f) * 0.5f);
                while (ti * (ti + 1) / 2 > t) --ti;
                while ((ti + 1) * (ti + 2) / 2 <= t) ++ti;
                int tj = t - ti * (ti + 1) / 2;
                int i0 = j1 + 4 * ti, c0 = j1 + 4 * tj;
                float a[4][4];
#pragma unroll
                for (int r = 0; r < 4; ++r)
#pragma unroll
                    for (int c = 0; c < 4; ++c)
                        a[r][c] = L[(i0 + r) * 193 + c0 + c];
#pragma unroll
                for (int k = 0; k < 16; ++k) {
                    float ar[4], bc[4];
#pragma unroll
                    for (int r = 0; r < 4; ++r) ar[r] = L[(i0 + r) * 193 + j0 + k];
#pragma unroll
                    for (int c = 0; c < 4; ++c) bc[c] = L[(c0 + c) * 193 + j0 + k];
#pragma unroll
                    for (int r = 0; r < 4; ++r)
#pragma unroll
                        for (int c = 0; c < 4; ++c)
                            a[r][c] -= ar[r] * bc[c];
                }
#pragma unroll
                for (int r = 0; r < 4; ++r)
#pragma unroll
                    for (int c = 0; c < 4; ++c)
                        L[(i0 + r) * 193 + c0 + c] = a[r][c];
            }
        }
        __syncthreads();
    }

    // fused tangent + FC
    float a0 = 0.f, a1 = 0.f, a2 = 0.f, a3 = 0.f;
    for (int d = tid; d < 192; d += 256) {
        float v = logf(fmaxf(L[d * 193 + d], 1e-30f));
        a0 += v * fcw[d];
        a1 += v * fcw[18528 + d];
        a2 += v * fcw[2 * 18528 + d];
        a3 += v * fcw[3 * 18528 + d];
    }
    for (int e = tid; e < 18336; e += 256) {
        float fe = (float)e;
        int r = (int)((1.0f + sqrtf(1.0f + 8.0f * fe)) * 0.5f);
        if (r < 1) r = 1;
        while (r * (r - 1) / 2 > e) --r;
        while ((r + 1) * r / 2 <= e) ++r;
        int c = e - r * (r - 1) / 2;
        float v = L[r * 193 + c];
        int dd = 192 + e;
        a0 += v * fcw[dd];
        a1 += v * fcw[18528 + dd];
        a2 += v * fcw[2 * 18528 + dd];
        a3 += v * fcw[3 * 18528 + dd];
    }
    for (int off = 32; off > 0; off >>= 1) {
        a0 += __shfl_down(a0, off);
        a1 += __shfl_down(a1, off);
        a2 += __shfl_down(a2, off);
        a3 += __shfl_down(a3, off);
    }
    int wv = tid >> 6, ln = tid & 63;
    if (ln == 0) { red[wv][0] = a0; red[wv][1] = a1; red[wv][2] = a2; red[wv][3] = a3; }
    __syncthreads();
    if (tid < 4) {
        float s = red[0][tid] + red[1][tid] + red[2][tid] + red[3][tid] + fcb[tid];
        out[b * 4 + tid] = s;
    }
}

// ---------------------------------------------------------------------------
extern "C" void kernel_launch(void* const* d_in, const int* in_sizes, int n_in,
                              void* d_out, int out_size, void* d_ws, size_t ws_size,
                              hipStream_t stream)
{
    float* ws = (float*)d_ws;

    prep_kernel<<<57, 256, 0, stream>>>(
        (const float*)d_in[1], (const float*)d_in[3], (const float*)d_in[5],
        (const float*)d_in[7], (const float*)d_in[9],
        (const float*)d_in[2], (const float*)d_in[4], (const float*)d_in[6],
        (const float*)d_in[8], (const float*)d_in[10],
        (const float*)d_in[11], (const float*)d_in[12], (const float*)d_in[13],
        (const float*)d_in[14],
        (const float*)d_in[15], (const float*)d_in[19], (const float*)d_in[23],
        (const float*)d_in[16], (const float*)d_in[20], (const float*)d_in[24],
        (const float*)d_in[17], (const float*)d_in[21], (const float*)d_in[25],
        (const float*)d_in[18], (const float*)d_in[22], (const float*)d_in[26], ws);
    xs_kernel<<<500, 256, 0, stream>>>((const float*)d_in[0], ws);
    if (ws_size >= WS_NEED) {
        xt_kernel<<<1024, 256, 0, stream>>>(ws);      // conv once, no redundancy
        gram_kernel<<<768, 256, 0, stream>>>(ws);     // MFMA batched GEMM
    } else {
        cov_kernel<<<768, 256, 0, stream>>>(ws);      // r8 fused fallback
    }
    chol_kernel<<<128, 256, 0, stream>>>(ws, (const float*)d_in[27],
                                         (const float*)d_in[28], (float*)d_out);
}

// Round 10
// 431.352 us; speedup vs baseline: 4.2649x; 1.1774x over previous
//
#include <hip/hip_runtime.h>
#include <hip/hip_bf16.h>
#include <math.h>

// ---- problem constants ----
// B=128, NC=64, T=1000, SPATIAL_MERGE=32, FILTERS={41,51,61}, NF=192
// FEATURE_DIM = {(3,4),(4,8),(4,16),(7,32),(240,64)}, SUM_SP=1078
// FC_IN = 18528, N_CLASS=4.  Input/output dtype: float32 (confirmed r6/r7).

// workspace layout (float offsets)
#define A_OFF    0         // 32*64
#define BETA_OFF 2048      // 32
#define TBE_OFF  2080      // 192
#define TWE_OFF  2304      // 3*4096, taps zero-padded to 64
#define XS_OFF   14592     // 128*32*1000 = 4,096,000
#define XBP_OFF  4110592   // 128 * 6 tiles * 64*64 packed (end 7,256,320 floats)
#define XT_OFF   7256320   // bf16 Xt [b][192][1024] = 12,582,912 floats worth
#define WS_NEED  ((size_t)19839232 * 4)   // 79.4 MB -> split path; else fused

#define SBN 0.9999950000374997f   // 1/sqrt(1+1e-5)

typedef short short8 __attribute__((ext_vector_type(8)));    // 8 bf16 (4 VGPRs)
typedef float floatx4 __attribute__((ext_vector_type(4)));   // MFMA accumulator

__device__ __forceinline__ unsigned short f2bf(float f) {    // fp32 -> bf16 (RNE)
    unsigned u = __float_as_uint(f);
    u += 0x7FFFu + ((u >> 16) & 1u);
    return (unsigned short)(u >> 16);
}
__device__ __forceinline__ float bf2f(unsigned short h) {
    return __uint_as_float(((unsigned)h) << 16);
}

// ---------------------------------------------------------------------------
// K1 (r10 rewrite): wave-parallel folding. One 64-lane wave per A_eff[m][c]
// (2048 waves) / per beta[m] (32 waves); lanes stride the 1078-term flat
// feature index; shfl-reduce. Elementwise tail: tbe + twe (padded to 64).
// Term set identical to r9 (verified); only summation order changes.
// ---------------------------------------------------------------------------
__global__ __launch_bounds__(256) void prep_kernel(
    const float* __restrict__ sw0, const float* __restrict__ sw1,
    const float* __restrict__ sw2, const float* __restrict__ sw3,
    const float* __restrict__ sw4,
    const float* __restrict__ sb0, const float* __restrict__ sb1,
    const float* __restrict__ sb2, const float* __restrict__ sb3,
    const float* __restrict__ sb4,
    const float* __restrict__ mw, const float* __restrict__ mb,
    const float* __restrict__ mg, const float* __restrict__ mbt,
    const float* __restrict__ tw0, const float* __restrict__ tw1,
    const float* __restrict__ tw2,
    const float* __restrict__ tb0, const float* __restrict__ tb1,
    const float* __restrict__ tb2,
    const float* __restrict__ tg0, const float* __restrict__ tg1,
    const float* __restrict__ tg2,
    const float* __restrict__ tbt0, const float* __restrict__ tbt1,
    const float* __restrict__ tbt2,
    float* __restrict__ ws)
{
    const float* tws[3]  = {tw0, tw1, tw2};
    const float* tbs[3]  = {tb0, tb1, tb2};
    const float* tgs[3]  = {tg0, tg1, tg2};
    const float* tbts[3] = {tbt0, tbt1, tbt2};
    const int fsz[3] = {41, 51, 61};

    int gid = blockIdx.x * 256 + threadIdx.x;
    int gw = gid >> 6, lane = gid & 63;

    if (gw < 2048) {
        // A_eff[m][c] — wave-parallel over 1078 terms
        int m = gw >> 6, c = gw & 63;
        float acc = 0.f;
        for (int j = lane; j < 1078; j += 64) {
            float wv = mw[m * 1078 + j];
            float sv = 0.f;
            if (j < 183) {
                int r = j, fq = r / 61, h = r - fq * 61, k = c - h;
                if (k >= 0 && k < 4)  sv = sw0[fq * 4 + k];
            } else if (j < 411) {
                int r = j - 183, fq = r / 57, h = r - fq * 57, k = c - h;
                if (k >= 0 && k < 8)  sv = sw1[fq * 8 + k];
            } else if (j < 607) {
                int r = j - 411, fq = r / 49, h = r - fq * 49, k = c - h;
                if (k >= 0 && k < 16) sv = sw2[fq * 16 + k];
            } else if (j < 838) {
                int r = j - 607, fq = r / 33, h = r - fq * 33, k = c - h;
                if (k >= 0 && k < 32) sv = sw3[fq * 32 + k];
            } else {
                int r = j - 838;                 // nc1=1: h=0, k=c always valid
                sv = sw4[r * 64 + c];
            }
            acc += wv * sv;
        }
        for (int off = 32; off > 0; off >>= 1) acc += __shfl_down(acc, off);
        if (lane == 0) ws[A_OFF + m * 64 + c] = mg[m] * SBN * acc;
    } else if (gw < 2080) {
        // beta_eff[m]
        int m = gw - 2048;
        float acc = 0.f;
        for (int j = lane; j < 1078; j += 64) {
            float wv = mw[m * 1078 + j];
            float sv;
            if (j < 183)      sv = sb0[j / 61];
            else if (j < 411) sv = sb1[(j - 183) / 57];
            else if (j < 607) sv = sb2[(j - 411) / 49];
            else if (j < 838) sv = sb3[(j - 607) / 33];
            else              sv = sb4[j - 838];
            acc += wv * sv;
        }
        for (int off = 32; off > 0; off >>= 1) acc += __shfl_down(acc, off);
        if (lane == 0)
            ws[BETA_OFF + m] = mg[m] * SBN * (acc + mb[m]) + mbt[m];
    } else {
        int id2 = gid - 133120;                  // 2080 waves * 64
        if (id2 < 0) return;
        if (id2 < 192) {
            int fi = id2 >> 6, o = id2 & 63;
            ws[TBE_OFF + id2] = tgs[fi][o] * SBN * tbs[fi][o] + tbts[fi][o];
        } else if (id2 < 12480) {
            int idx = id2 - 192;
            int fi = idx >> 12, r = idx & 4095, o = r >> 6, k = r & 63;
            int sz = fsz[fi];
            float v = 0.f;
            if (k < sz) v = tgs[fi][o] * SBN * tws[fi][o * sz + k];
            ws[TWE_OFF + idx] = v;
        }
    }
}

// ---------------------------------------------------------------------------
// K2: Xs[b][m][t] = A_eff[m,:] . x[b,:,t] + beta[m]  (verified)
// ---------------------------------------------------------------------------
__global__ __launch_bounds__(256) void xs_kernel(const float* __restrict__ x,
                                                 float* __restrict__ ws)
{
    __shared__ float Ash[2048];
    __shared__ float Bsh[32];
    int tid = threadIdx.x;
    for (int i = tid; i < 2048; i += 256) Ash[i] = ws[A_OFF + i];
    if (tid < 32) Bsh[tid] = ws[BETA_OFF + tid];
    __syncthreads();

    int gid = blockIdx.x * 256 + tid;
    int b = gid / 1000, t = gid - b * 1000;
    const float* xp = x + b * 64000 + t;

    float acc[32];
#pragma unroll
    for (int m = 0; m < 32; ++m) acc[m] = Bsh[m];
#pragma unroll 4
    for (int c = 0; c < 64; ++c) {
        float xv = xp[c * 1000];
#pragma unroll
        for (int m = 0; m < 32; ++m) acc[m] += Ash[m * 64 + c] * xv;
    }
    float* op = ws + XS_OFF + b * 32000 + t;
#pragma unroll
    for (int m = 0; m < 32; ++m) op[m * 1000] = acc[m];
}

// ---------------------------------------------------------------------------
// conv8: rolling 8-output register window, bf16 weights (verified r8/r9)
// ---------------------------------------------------------------------------
__device__ __forceinline__ void conv8_vals(float* __restrict__ a,
                                           const float* __restrict__ xp,
                                           const unsigned short* __restrict__ wp,
                                           int szp, float bias)
{
    float xw[8];
#pragma unroll
    for (int i = 0; i < 8; ++i) { a[i] = bias; xw[i] = xp[i]; }
    for (int k = 0; k < szp; k += 8) {
#pragma unroll
        for (int p = 0; p < 8; ++p) {
            float w = bf2f(wp[(k + p) * 64]);
#pragma unroll
            for (int i = 0; i < 8; ++i) a[i] += w * xw[(p + i) & 7];
            xw[p] = xp[k + p + 8];
        }
    }
}

// ---------------------------------------------------------------------------
// K3a: compute Xt bf16 once to global ws[b][192][1024]  (verified r9)
// ---------------------------------------------------------------------------
__global__ __launch_bounds__(256) void xt_kernel(float* __restrict__ ws)
{
    __shared__ float xs_sh[32 * 200];
    __shared__ unsigned short tw_sh[10752];
    __shared__ float tb_sh[192];

    int tid = threadIdx.x;
    int wg = blockIdx.x;
    int b = wg >> 3, chunk = wg & 7;
    int t0 = chunk * 128;
    const int fszp[3]  = {48, 56, 64};
    const int fpad[3]  = {20, 25, 30};
    const int twoff[3] = {0, 3072, 6656};

    for (int idx = tid; idx < 10752; idx += 256) {
        int bank, kt, rem;
        if (idx < 3072)      { bank = 0; rem = idx; }
        else if (idx < 6656) { bank = 1; rem = idx - 3072; }
        else                 { bank = 2; rem = idx - 6656; }
        kt = rem >> 6; int o = rem & 63;
        tw_sh[idx] = f2bf(ws[TWE_OFF + bank * 4096 + o * 64 + kt]);
    }
    if (tid < 192) tb_sh[tid] = ws[TBE_OFF + tid];

    const float* xsrow = ws + XS_OFF + b * 32000;
    for (int idx = tid; idx < 6400; idx += 256) {
        int m = idx / 200, q = idx - m * 200;
        int gt = t0 - 30 + q;
        xs_sh[m * 200 + q] = (gt >= 0 && gt < 1000) ? xsrow[m * 1000 + gt] : 0.f;
    }
    __syncthreads();

    unsigned short* xtg = (unsigned short*)(ws + XT_OFF);
    for (int it = 0; it < 12; ++it) {
        int task = it * 256 + tid;
        int ch = task >> 4, tg = task & 15;
        int bank = ch >> 6, o = ch & 63, m = o >> 1;
        int tlb = tg * 8;
        float a[8];
        conv8_vals(a, &xs_sh[m * 200 + tlb + (30 - fpad[bank])],
                   &tw_sh[twoff[bank] + o], fszp[bank], tb_sh[ch]);
        short8 hv;
#pragma unroll
        for (int i = 0; i < 8; ++i) {
            int gt = t0 + tlb + i;
            hv[i] = (short)((gt < 1000) ? f2bf(a[i]) : 0);
        }
        *(short8*)&xtg[(size_t)(b * 192 + ch) * 1024 + t0 + tlb] = hv;
    }
}

// ---------------------------------------------------------------------------
// K3b (r10 rewrite): Gram MFMA, 2 blocks per batch (grid 256 = CU count).
// h=0: stages banks 0-1, computes tiles (0,0),(1,0),(1,1) [ids 0,1,2].
// h=1: stages banks 0-2, computes tiles (2,0),(2,1),(2,2) [ids 3,4,5].
// Xt read once per block (A-frag shared across its 3 tiles).
// ---------------------------------------------------------------------------
__global__ __launch_bounds__(256) void gram_kernel(float* __restrict__ ws)
{
    __shared__ __align__(16) unsigned short xsh[192 * 136];   // 52,224 B

    int tid = threadIdx.x;
    int b = blockIdx.x >> 1, h = blockIdx.x & 1;
    int nrows = h ? 192 : 128;

    const unsigned short* xtg = (const unsigned short*)(ws + XT_OFF);
    const unsigned short* gb = xtg + (size_t)b * 192 * 1024;

    floatx4 acc[3][4];
#pragma unroll
    for (int t = 0; t < 3; ++t)
#pragma unroll
        for (int sj = 0; sj < 4; ++sj) acc[t][sj] = (floatx4){0.f, 0.f, 0.f, 0.f};

    const int lane = tid & 63;
    const int wv   = tid >> 6;
    const int m15  = lane & 15;
    const int quad = lane >> 4;
    int nloads = nrows * 16;

    for (int t0 = 0; t0 < 1024; t0 += 128) {
        for (int idx = tid; idx < nloads; idx += 256) {
            int row = idx >> 4, c8 = idx & 15;
            *(short8*)&xsh[row * 136 + c8 * 8] =
                *(const short8*)&gb[(size_t)row * 1024 + t0 + c8 * 8];
        }
        __syncthreads();
        if (h == 0) {
#pragma unroll
            for (int k0 = 0; k0 < 128; k0 += 32) {
                short8 a0 = *(const short8*)&xsh[(      wv * 16 + m15) * 136 + quad * 8 + k0];
                short8 a1 = *(const short8*)&xsh[( 64 + wv * 16 + m15) * 136 + quad * 8 + k0];
#pragma unroll
                for (int sj = 0; sj < 4; ++sj) {
                    short8 b0 = *(const short8*)&xsh[(      sj * 16 + m15) * 136 + quad * 8 + k0];
                    short8 b1 = *(const short8*)&xsh[( 64 + sj * 16 + m15) * 136 + quad * 8 + k0];
                    acc[0][sj] = __builtin_amdgcn_mfma_f32_16x16x32_bf16(a0, b0, acc[0][sj], 0, 0, 0);
                    acc[1][sj] = __builtin_amdgcn_mfma_f32_16x16x32_bf16(a1, b0, acc[1][sj], 0, 0, 0);
                    acc[2][sj] = __builtin_amdgcn_mfma_f32_16x16x32_bf16(a1, b1, acc[2][sj], 0, 0, 0);
                }
            }
        } else {
#pragma unroll
            for (int k0 = 0; k0 < 128; k0 += 32) {
                short8 a2 = *(const short8*)&xsh[(128 + wv * 16 + m15) * 136 + quad * 8 + k0];
#pragma unroll
                for (int sj = 0; sj < 4; ++sj) {
                    short8 b0 = *(const short8*)&xsh[(      sj * 16 + m15) * 136 + quad * 8 + k0];
                    short8 b1 = *(const short8*)&xsh[( 64 + sj * 16 + m15) * 136 + quad * 8 + k0];
                    short8 b2 = *(const short8*)&xsh[(128 + sj * 16 + m15) * 136 + quad * 8 + k0];
                    acc[0][sj] = __builtin_amdgcn_mfma_f32_16x16x32_bf16(a2, b0, acc[0][sj], 0, 0, 0);
                    acc[1][sj] = __builtin_amdgcn_mfma_f32_16x16x32_bf16(a2, b1, acc[1][sj], 0, 0, 0);
                    acc[2][sj] = __builtin_amdgcn_mfma_f32_16x16x32_bf16(a2, b2, acc[2][sj], 0, 0, 0);
                }
            }
        }
        __syncthreads();
    }

    const float sc = 1.0f / 999.0f;
#pragma unroll
    for (int t = 0; t < 3; ++t) {
        int tileid = h ? (3 + t) : t;
        float* xbp = ws + XBP_OFF + b * 24576 + tileid * 4096;
#pragma unroll
        for (int sj = 0; sj < 4; ++sj)
#pragma unroll
            for (int r = 0; r < 4; ++r) {
                int i = wv * 16 + quad * 4 + r;     // C/D: row = quad*4 + reg
                int j = sj * 16 + m15;              //      col = lane & 15
                xbp[i * 64 + j] = acc[t][sj][r] * sc;
            }
    }
}

// ---------------------------------------------------------------------------
// K3 (fallback, small ws): r8's fused conv+Gram kernel (verified).
// ---------------------------------------------------------------------------
__global__ __launch_bounds__(256, 3) void cov_kernel(float* __restrict__ ws)
{
    __shared__ float xs_sh[32 * 129];
    __shared__ __align__(16) unsigned short xt_sh[2 * 64 * 72];
    __shared__ unsigned short tw_sh[120 * 64];
    __shared__ float tb_sh[128];

    int tid = threadIdx.x;
    int wg = blockIdx.x;
    int b = wg / 6, tile = wg - b * 6;
    const int TIa[6] = {0, 1, 1, 2, 2, 2};
    const int TJa[6] = {0, 0, 1, 0, 1, 2};
    int I = TIa[tile], J = TJa[tile];
    const int fpad[3] = {20, 25, 30};
    const int fszp[3] = {48, 56, 64};
    int padI = fpad[I], szpI = fszp[I];
    int padJ = fpad[J], szpJ = fszp[J];
    bool diag = (I == J);

    int nI = szpI * 64;
    for (int idx = tid; idx < nI; idx += 256) {
        int kt = idx >> 6, o = idx & 63;
        tw_sh[idx] = f2bf(ws[TWE_OFF + I * 4096 + o * 64 + kt]);
    }
    if (!diag) {
        int nJ = szpJ * 64;
        for (int idx = tid; idx < nJ; idx += 256) {
            int kt = idx >> 6, o = idx & 63;
            tw_sh[nI + idx] = f2bf(ws[TWE_OFF + J * 4096 + o * 64 + kt]);
        }
    }
    if (tid < 64)        tb_sh[tid] = ws[TBE_OFF + I * 64 + tid];
    else if (tid < 128)  tb_sh[tid] = ws[TBE_OFF + J * 64 + (tid - 64)];

    floatx4 acc[4];
#pragma unroll
    for (int sj = 0; sj < 4; ++sj) acc[sj] = (floatx4){0.f, 0.f, 0.f, 0.f};

    const float* xsrow = ws + XS_OFF + b * 32000;
    unsigned short* xtI = xt_sh;
    unsigned short* xtJ = diag ? xt_sh : (xt_sh + 64 * 72);

    const int lane = tid & 63;
    const int wv   = tid >> 6;
    const int m15  = lane & 15;
    const int quad = lane >> 4;

    for (int t0 = 0; t0 < 1000; t0 += 64) {
        for (int idx = tid; idx < 4096; idx += 256) {
            int m = idx >> 7, q = idx & 127;
            int gt = t0 - 30 + q;
            xs_sh[m * 129 + q] = (gt >= 0 && gt < 1000) ? xsrow[m * 1000 + gt] : 0.f;
        }
        __syncthreads();
        for (int it = 0; it < 2; ++it) {
            int o   = lane;
            int grp = wv + it * 4;
            int tlb = grp * 8;
            int m   = o >> 1;
            float a[8];
            conv8_vals(a, &xs_sh[m * 129 + tlb + (30 - padI)], &tw_sh[o],
                       szpI, tb_sh[o]);
            short8 hv;
#pragma unroll
            for (int i = 0; i < 8; ++i) {
                int gt = t0 + tlb + i;
                hv[i] = (short)((gt < 1000) ? f2bf(a[i]) : 0);
            }
            *(short8*)&xtI[o * 72 + tlb] = hv;
            if (!diag) {
                conv8_vals(a, &xs_sh[m * 129 + tlb + (30 - padJ)], &tw_sh[nI + o],
                           szpJ, tb_sh[64 + o]);
#pragma unroll
                for (int i = 0; i < 8; ++i) {
                    int gt = t0 + tlb + i;
                    hv[i] = (short)((gt < 1000) ? f2bf(a[i]) : 0);
                }
                *(short8*)&xtJ[o * 72 + tlb] = hv;
            }
        }
        __syncthreads();
        const unsigned short* ap = &xtI[(wv * 16 + m15) * 72 + quad * 8];
#pragma unroll
        for (int k0 = 0; k0 < 64; k0 += 32) {
            short8 af = *(const short8*)(ap + k0);
#pragma unroll
            for (int sj = 0; sj < 4; ++sj) {
                short8 bf = *(const short8*)&xtJ[(sj * 16 + m15) * 72 + quad * 8 + k0];
                acc[sj] = __builtin_amdgcn_mfma_f32_16x16x32_bf16(af, bf, acc[sj],
                                                                  0, 0, 0);
            }
        }
        __syncthreads();
    }

    float* xbp = ws + XBP_OFF + b * 24576 + tile * 4096;
    const float sc = 1.0f / 999.0f;
#pragma unroll
    for (int sj = 0; sj < 4; ++sj)
#pragma unroll
        for (int r = 0; r < 4; ++r) {
            int i = wv * 16 + quad * 4 + r;
            int j = sj * 16 + m15;
            xbp[i * 64 + j] = acc[sj][r] * sc;
        }
}

// ---------------------------------------------------------------------------
// K4: per-batch blocked Cholesky (NB=16). r9 A/TRSM (verified) + r10
// trailing update in 8x8 register tiles (-38% LDS lane-ops vs 4x4).
// 8-aligned tiles never straddle 64-blocks; diag-tile upper entries are
// garbage-in/garbage-out and never read downstream.
// ---------------------------------------------------------------------------
__global__ __launch_bounds__(256) void chol_kernel(const float* __restrict__ ws,
                                                   const float* __restrict__ fcw,
                                                   const float* __restrict__ fcb,
                                                   float* __restrict__ out)
{
    __shared__ float L[192 * 193];   // 148,224 B
    __shared__ float invd_sh[16];
    __shared__ float red[4][4];

    int b = blockIdx.x, tid = threadIdx.x;
    const float* Xb = ws + XBP_OFF + b * 24576;
    const int TIa[6] = {0, 1, 1, 2, 2, 2};
    const int TJa[6] = {0, 0, 1, 0, 1, 2};

    for (int idx = tid; idx < 24576; idx += 256) {
        int t = idx >> 12, r = (idx >> 6) & 63, c = idx & 63;
        L[(TIa[t] * 64 + r) * 193 + TJa[t] * 64 + c] = Xb[idx];
    }
    __syncthreads();

    for (int p = 0; p < 12; ++p) {
        int j0 = p * 16, j1 = j0 + 16;
        // --- A: 16x16 diag Cholesky in registers (lanes 0-15, shuffles) ---
        if (tid < 16) {
            int i = tid;
            float r[16];
#pragma unroll
            for (int c = 0; c < 16; ++c) r[c] = L[(j0 + i) * 193 + j0 + c];
#pragma unroll
            for (int jj = 0; jj < 16; ++jj) {
                float d = __shfl(r[jj], jj);
                d = fmaxf(d, 1e-20f);
                float s = sqrtf(d);
                float inv = 1.0f / s;
                if (i == jj) { r[jj] = s; invd_sh[jj] = inv; }
                else if (i > jj) r[jj] *= inv;
#pragma unroll
                for (int cc = jj + 1; cc < 16; ++cc) {
                    float vc = __shfl(r[jj], cc);
                    if (i >= cc) r[cc] -= r[jj] * vc;
                }
            }
#pragma unroll
            for (int c = 0; c < 16; ++c)
                if (c <= i) L[(j0 + i) * 193 + j0 + c] = r[c];
        }
        __syncthreads();
        if (j1 < 192) {
            // --- B: TRSM, one row per thread, inv-diag multiplies ---
            int i = j1 + tid;
            if (i < 192) {
                float v[16];
                float* row = &L[i * 193 + j0];
#pragma unroll
                for (int k = 0; k < 16; ++k) v[k] = row[k];
#pragma unroll
                for (int k = 0; k < 16; ++k) {
                    float vk = v[k];
#pragma unroll
                    for (int p2 = 0; p2 < k; ++p2)
                        vk -= v[p2] * L[(j0 + k) * 193 + j0 + p2];
                    v[k] = vk * invd_sh[k];
                }
#pragma unroll
                for (int k = 0; k < 16; ++k) row[k] = v[k];
            }
            __syncthreads();
            // --- C: trailing rank-16 update, 8x8 reg tiles ---
            int RT = (192 - j1) >> 3;
            int ntiles = RT * (RT + 1) / 2;
            for (int t = tid; t < ntiles; t += 256) {
                int ti = (int)((sqrtf(8.0f * (float)t + 1.0f) - 1.0f) * 0.5f);
                while (ti * (ti + 1) / 2 > t) --ti;
                while ((ti + 1) * (ti + 2) / 2 <= t) ++ti;
                int tj = t - ti * (ti + 1) / 2;
                int i0 = j1 + 8 * ti, c0 = j1 + 8 * tj;
                float a[8][8];
#pragma unroll
                for (int r = 0; r < 8; ++r)
#pragma unroll
                    for (int c = 0; c < 8; ++c)
                        a[r][c] = L[(i0 + r) * 193 + c0 + c];
#pragma unroll
                for (int k = 0; k < 16; ++k) {
                    float ar[8], bc[8];
#pragma unroll
                    for (int r = 0; r < 8; ++r) ar[r] = L[(i0 + r) * 193 + j0 + k];
#pragma unroll
                    for (int c = 0; c < 8; ++c) bc[c] = L[(c0 + c) * 193 + j0 + k];
#pragma unroll
                    for (int r = 0; r < 8; ++r)
#pragma unroll
                        for (int c = 0; c < 8; ++c)
                            a[r][c] -= ar[r] * bc[c];
                }
#pragma unroll
                for (int r = 0; r < 8; ++r)
#pragma unroll
                    for (int c = 0; c < 8; ++c)
                        L[(i0 + r) * 193 + c0 + c] = a[r][c];
            }
        }
        __syncthreads();
    }

    // fused tangent + FC
    float a0 = 0.f, a1 = 0.f, a2 = 0.f, a3 = 0.f;
    for (int d = tid; d < 192; d += 256) {
        float v = logf(fmaxf(L[d * 193 + d], 1e-30f));
        a0 += v * fcw[d];
        a1 += v * fcw[18528 + d];
        a2 += v * fcw[2 * 18528 + d];
        a3 += v * fcw[3 * 18528 + d];
    }
    for (int e = tid; e < 18336; e += 256) {
        float fe = (float)e;
        int r = (int)((1.0f + sqrtf(1.0f + 8.0f * fe)) * 0.5f);
        if (r < 1) r = 1;
        while (r * (r - 1) / 2 > e) --r;
        while ((r + 1) * r / 2 <= e) ++r;
        int c = e - r * (r - 1) / 2;
        float v = L[r * 193 + c];
        int dd = 192 + e;
        a0 += v * fcw[dd];
        a1 += v * fcw[18528 + dd];
        a2 += v * fcw[2 * 18528 + dd];
        a3 += v * fcw[3 * 18528 + dd];
    }
    for (int off = 32; off > 0; off >>= 1) {
        a0 += __shfl_down(a0, off);
        a1 += __shfl_down(a1, off);
        a2 += __shfl_down(a2, off);
        a3 += __shfl_down(a3, off);
    }
    int wv = tid >> 6, ln = tid & 63;
    if (ln == 0) { red[wv][0] = a0; red[wv][1] = a1; red[wv][2] = a2; red[wv][3] = a3; }
    __syncthreads();
    if (tid < 4) {
        float s = red[0][tid] + red[1][tid] + red[2][tid] + red[3][tid] + fcb[tid];
        out[b * 4 + tid] = s;
    }
}

// ---------------------------------------------------------------------------
extern "C" void kernel_launch(void* const* d_in, const int* in_sizes, int n_in,
                              void* d_out, int out_size, void* d_ws, size_t ws_size,
                              hipStream_t stream)
{
    float* ws = (float*)d_ws;

    prep_kernel<<<569, 256, 0, stream>>>(
        (const float*)d_in[1], (const float*)d_in[3], (const float*)d_in[5],
        (const float*)d_in[7], (const float*)d_in[9],
        (const float*)d_in[2], (const float*)d_in[4], (const float*)d_in[6],
        (const float*)d_in[8], (const float*)d_in[10],
        (const float*)d_in[11], (const float*)d_in[12], (const float*)d_in[13],
        (const float*)d_in[14],
        (const float*)d_in[15], (const float*)d_in[19], (const float*)d_in[23],
        (const float*)d_in[16], (const float*)d_in[20], (const float*)d_in[24],
        (const float*)d_in[17], (const float*)d_in[21], (const float*)d_in[25],
        (const float*)d_in[18], (const float*)d_in[22], (const float*)d_in[26], ws);
    xs_kernel<<<500, 256, 0, stream>>>((const float*)d_in[0], ws);
    if (ws_size >= WS_NEED) {
        xt_kernel<<<1024, 256, 0, stream>>>(ws);      // conv once
        gram_kernel<<<256, 256, 0, stream>>>(ws);     // 2 blocks/batch MFMA
    } else {
        cov_kernel<<<768, 256, 0, stream>>>(ws);      // r8 fused fallback
    }
    chol_kernel<<<128, 256, 0, stream>>>(ws, (const float*)d_in[27],
                                         (const float*)d_in[28], (float*)d_out);
}